// Round 3
// baseline (929.667 us; speedup 1.0000x reference)
//
#include <hip/hip_runtime.h>

#define NN 131072   // nodes
#define NE 524288   // edges
#define NG 4096     // graphs

// ---------------- preprocessing: degree, dis, CSR ----------------

__global__ void k_count(const int* __restrict__ dst, int* __restrict__ counts) {
    int e = blockIdx.x * blockDim.x + threadIdx.x;
    if (e < NE) atomicAdd(&counts[dst[e]], 1);
}

__global__ void k_dis(const int* __restrict__ counts, float* __restrict__ dis) {
    int i = blockIdx.x * blockDim.x + threadIdx.x;
    if (i < NN) dis[i] = rsqrtf((float)(counts[i] + 1));  // +1 self-loop; deg>=1 always
}

__global__ void k_scanA(const int* __restrict__ in, int* __restrict__ out, int* __restrict__ bsum) {
    __shared__ int s[256];
    int t = threadIdx.x;
    int i = blockIdx.x * 256 + t;
    int v = in[i];
    s[t] = v;
    __syncthreads();
    for (int off = 1; off < 256; off <<= 1) {
        int x = (t >= off) ? s[t - off] : 0;
        __syncthreads();
        s[t] += x;
        __syncthreads();
    }
    out[i] = s[t] - v;                  // exclusive
    if (t == 255) bsum[blockIdx.x] = s[t];
}

__global__ void k_scanB(int* __restrict__ bsum) {   // 512 block sums, 1 block
    __shared__ int s[512];
    int t = threadIdx.x;
    int v = bsum[t];
    s[t] = v;
    __syncthreads();
    for (int off = 1; off < 512; off <<= 1) {
        int x = (t >= off) ? s[t - off] : 0;
        __syncthreads();
        s[t] += x;
        __syncthreads();
    }
    bsum[t] = s[t] - v;                 // exclusive
}

__global__ void k_scanC(int* __restrict__ rowstart, const int* __restrict__ bsum) {
    int t = threadIdx.x;
    int i = blockIdx.x * 256 + t;
    rowstart[i] += bsum[blockIdx.x];
    if (i == 0) rowstart[NN] = NE;
}

__global__ void k_fill(const int* __restrict__ src, const int* __restrict__ dst,
                       const int* __restrict__ rowstart, int* __restrict__ cursor,
                       const float* __restrict__ dis,
                       int* __restrict__ col, float* __restrict__ wgt) {
    int e = blockIdx.x * blockDim.x + threadIdx.x;
    if (e >= NE) return;
    int s = src[e], d = dst[e];
    int pos = rowstart[d] + atomicAdd(&cursor[d], 1);
    col[pos] = s;
    wgt[pos] = dis[s] * dis[d];
}

// ---------------- aggregation: out[i] = dis[i]^2*h[i] + sum_e norm*h[src] ----------------

template<int C>
__global__ __launch_bounds__(256)
void k_agg(const float* __restrict__ hin, const int* __restrict__ rowstart,
           const int* __restrict__ col, const float* __restrict__ wgt,
           const float* __restrict__ dis, float* __restrict__ out) {
    const int total = NN * C;
    for (int idx = blockIdx.x * 256 + threadIdx.x; idx < total; idx += gridDim.x * 256) {
        int i = idx / C;
        int c = idx - i * C;
        float d = dis[i];
        float acc = d * d * hin[i * C + c];
        int j1 = rowstart[i + 1];
        for (int j = rowstart[i]; j < j1; ++j) {
            acc = fmaf(wgt[j], hin[col[j] * C + c], acc);
        }
        out[idx] = acc;
    }
}

// ---------------- GEMM: out = relu(A @ W + b); optional fused segment-max pool ----------------
// 64x64 tile, BK=8, 256 threads, 4x4 microtile. M must be a multiple of 64.

template<int CI, int CO, bool RELU, bool POOL>
__global__ __launch_bounds__(256)
void k_gemm(const float* __restrict__ A, const float* __restrict__ Wm,
            const float* __restrict__ bias, float* __restrict__ out,
            const int* __restrict__ batch, float* __restrict__ pooled) {
    __shared__ float sA[8][68];
    __shared__ float sB[8][68];
    __shared__ float sp[2][64];
    __shared__ int s_uni[2];

    const int tid = threadIdx.x;
    const int tx = tid & 15;
    const int ty = tid >> 4;
    const int row0 = blockIdx.y * 64;
    const int col0 = blockIdx.x * 64;

    if (POOL) {
        if (tid < 128) sp[tid >> 6][tid & 63] = 0.0f;
        if (tid == 0) {
            // batch is sorted: endpoints equal => whole 32-row group is one graph
            s_uni[0] = (batch[row0]      == batch[row0 + 31]);
            s_uni[1] = (batch[row0 + 32] == batch[row0 + 63]);
        }
    }

    float acc[4][4] = {};

    const int la_k = tid & 7;     // 0..7
    const int la_m = tid >> 3;    // 0..31
    const int lb_c = tid & 63;    // 0..63
    const int lb_k = tid >> 6;    // 0..3

    for (int k0 = 0; k0 < CI; k0 += 8) {
        #pragma unroll
        for (int mm = la_m; mm < 64; mm += 32) {
            float v = 0.0f;
            if (k0 + la_k < CI) v = A[(row0 + mm) * CI + k0 + la_k];
            sA[la_k][mm] = v;
        }
        #pragma unroll
        for (int kk = lb_k; kk < 8; kk += 4) {
            float v = 0.0f;
            int col = col0 + lb_c;
            if (k0 + kk < CI && col < CO) v = Wm[(k0 + kk) * CO + col];
            sB[kk][lb_c] = v;
        }
        __syncthreads();
        #pragma unroll
        for (int kk = 0; kk < 8; ++kk) {
            float ra[4], rb[4];
            #pragma unroll
            for (int i = 0; i < 4; ++i) ra[i] = sA[kk][ty * 4 + i];
            #pragma unroll
            for (int j = 0; j < 4; ++j) rb[j] = sB[kk][tx * 4 + j];
            #pragma unroll
            for (int i = 0; i < 4; ++i)
                #pragma unroll
                for (int j = 0; j < 4; ++j)
                    acc[i][j] = fmaf(ra[i], rb[j], acc[i][j]);
        }
        __syncthreads();
    }

    float bv[4];
    #pragma unroll
    for (int j = 0; j < 4; ++j) {
        int col = col0 + tx * 4 + j;
        bv[j] = (col < CO) ? bias[col] : 0.0f;
    }

    if (!POOL) {
        #pragma unroll
        for (int i = 0; i < 4; ++i) {
            int row = row0 + ty * 4 + i;
            #pragma unroll
            for (int j = 0; j < 4; ++j) {
                int col = col0 + tx * 4 + j;
                if (col < CO) {
                    float v = acc[i][j] + bv[j];
                    if (RELU) v = fmaxf(v, 0.0f);
                    out[row * CO + col] = v;
                }
            }
        }
    } else {
        // fused relu + segment-max pool; h3 never materialized.
        const int grp = ty >> 3;   // which 32-row group this thread's 4 rows live in
        if (s_uni[grp]) {
            #pragma unroll
            for (int j = 0; j < 4; ++j) {
                int col = col0 + tx * 4 + j;
                if (col < CO) {
                    float mv = 0.0f;   // relu floor
                    #pragma unroll
                    for (int i = 0; i < 4; ++i) mv = fmaxf(mv, acc[i][j] + bv[j]);
                    atomicMax((int*)&sp[grp][tx * 4 + j], __float_as_int(mv));
                }
            }
        } else {
            // sorted-but-misaligned fallback: per-row atomics (never hit with 32/graph)
            #pragma unroll
            for (int i = 0; i < 4; ++i) {
                int row = row0 + ty * 4 + i;
                int g = batch[row];
                #pragma unroll
                for (int j = 0; j < 4; ++j) {
                    int col = col0 + tx * 4 + j;
                    if (col < CO) {
                        float v = fmaxf(acc[i][j] + bv[j], 0.0f);
                        atomicMax((int*)&pooled[g * CO + col], __float_as_int(v));
                    }
                }
            }
        }
        __syncthreads();
        if (tid < 128) {
            int g2 = tid >> 6, c = tid & 63;
            int col = col0 + c;
            if (col < CO && s_uni[g2]) {
                int g = batch[row0 + 32 * g2];
                atomicMax((int*)&pooled[g * CO + col], __float_as_int(sp[g2][c]));
            }
        }
    }
}

// ---------------- launch ----------------

extern "C" void kernel_launch(void* const* d_in, const int* in_sizes, int n_in,
                              void* d_out, int out_size, void* d_ws, size_t ws_size,
                              hipStream_t stream) {
    const float* x    = (const float*)d_in[0];
    const int*   ei   = (const int*)d_in[1];
    const int*   srcv = ei;            // edge_index[0]
    const int*   dstv = ei + NE;       // edge_index[1]
    const int*   batch = (const int*)d_in[2];
    const float* W1 = (const float*)d_in[3];
    const float* b1 = (const float*)d_in[4];
    const float* W2 = (const float*)d_in[5];
    const float* b2 = (const float*)d_in[6];
    const float* W3 = (const float*)d_in[7];
    const float* b3 = (const float*)d_in[8];
    const float* fcW = (const float*)d_in[9];
    const float* fcb = (const float*)d_in[10];
    float* out = (float*)d_out;

    char* ws = (char*)d_ws;
    size_t off = 0;
    auto take = [&](size_t bytes) -> void* {
        void* p = ws + off;
        off += (bytes + 255) & ~(size_t)255;
        return p;
    };
    int*   counts   = (int*)take((size_t)NN * 4);
    int*   rowstart = (int*)take((size_t)(NN + 1) * 4);
    int*   cursor   = (int*)take((size_t)NN * 4);
    float* dis      = (float*)take((size_t)NN * 4);
    int*   bsum     = (int*)take(512 * 4);
    int*   col      = (int*)take((size_t)NE * 4);
    float* wgt      = (float*)take((size_t)NE * 4);
    float* B0       = (float*)take((size_t)NN * 156 * 4);
    float* B1       = (float*)take((size_t)NN * 156 * 4);
    float* pooled   = (float*)take((size_t)NG * 312 * 4);

    hipMemsetAsync(counts, 0, (size_t)NN * 4, stream);
    hipMemsetAsync(cursor, 0, (size_t)NN * 4, stream);
    hipMemsetAsync(pooled, 0, (size_t)NG * 312 * 4, stream);

    k_count<<<NE / 256, 256, 0, stream>>>(dstv, counts);
    k_dis<<<NN / 256, 256, 0, stream>>>(counts, dis);
    k_scanA<<<NN / 256, 256, 0, stream>>>(counts, rowstart, bsum);
    k_scanB<<<1, 512, 0, stream>>>(bsum);
    k_scanC<<<NN / 256, 256, 0, stream>>>(rowstart, bsum);
    k_fill<<<NE / 256, 256, 0, stream>>>(srcv, dstv, rowstart, cursor, dis, col, wgt);

    // layer 1: agg(x) -> B0 ; relu(B0@W1+b1) -> B1
    k_agg<78><<<2048, 256, 0, stream>>>(x, rowstart, col, wgt, dis, B0);
    k_gemm<78, 78, true, false><<<dim3(2, NN / 64), 256, 0, stream>>>(B0, W1, b1, B1, nullptr, nullptr);
    // layer 2: agg(B1) -> B0 ; relu(B0@W2+b2) -> B1
    k_agg<78><<<2048, 256, 0, stream>>>(B1, rowstart, col, wgt, dis, B0);
    k_gemm<78, 156, true, false><<<dim3(3, NN / 64), 256, 0, stream>>>(B0, W2, b2, B1, nullptr, nullptr);
    // layer 3: agg(B1) -> B0 ; relu(B0@W3+b3) fused with segment-max -> pooled
    k_agg<156><<<2048, 256, 0, stream>>>(B1, rowstart, col, wgt, dis, B0);
    k_gemm<156, 312, true, true><<<dim3(5, NN / 64), 256, 0, stream>>>(B0, W3, b3, nullptr, batch, pooled);
    // FC: pooled @ fcW + fcb -> out (no relu)
    k_gemm<312, 128, false, false><<<dim3(2, NG / 64), 256, 0, stream>>>(pooled, fcW, fcb, out, nullptr, nullptr);
}

// Round 5
// 748.054 us; speedup vs baseline: 1.2428x; 1.2428x over previous
//
#include <hip/hip_runtime.h>

#define NN 131072   // nodes
#define NE 524288   // edges
#define NG 4096     // graphs
#define KP 160      // padded K for layer-3 bf16 path
#define LDSROW 168  // LDS row pitch in bf16 elems (336 B = 84 dwords -> 8-bank spread)

typedef __attribute__((ext_vector_type(8))) short bfx8;
typedef __attribute__((ext_vector_type(4))) float f32x4;

static __device__ __forceinline__ ushort f2bf(float f) {
    union { float f; unsigned u; } v; v.f = f;
    unsigned r = (v.u + 0x7fff + ((v.u >> 16) & 1)) >> 16;   // RNE
    return (ushort)r;
}

// ---------------- preprocessing: degree, dis, CSR ----------------

__global__ void k_count(const int* __restrict__ dst, int* __restrict__ counts) {
    int e = blockIdx.x * blockDim.x + threadIdx.x;
    if (e < NE) atomicAdd(&counts[dst[e]], 1);
}

__global__ void k_dis(const int* __restrict__ counts, float* __restrict__ dis) {
    int i = blockIdx.x * blockDim.x + threadIdx.x;
    if (i < NN) dis[i] = rsqrtf((float)(counts[i] + 1));  // +1 self-loop
}

__global__ void k_scanA(const int* __restrict__ in, int* __restrict__ out, int* __restrict__ bsum) {
    __shared__ int s[256];
    int t = threadIdx.x;
    int i = blockIdx.x * 256 + t;
    int v = in[i];
    s[t] = v;
    __syncthreads();
    for (int off = 1; off < 256; off <<= 1) {
        int x = (t >= off) ? s[t - off] : 0;
        __syncthreads();
        s[t] += x;
        __syncthreads();
    }
    out[i] = s[t] - v;
    if (t == 255) bsum[blockIdx.x] = s[t];
}

__global__ void k_scanB(int* __restrict__ bsum) {
    __shared__ int s[512];
    int t = threadIdx.x;
    int v = bsum[t];
    s[t] = v;
    __syncthreads();
    for (int off = 1; off < 512; off <<= 1) {
        int x = (t >= off) ? s[t - off] : 0;
        __syncthreads();
        s[t] += x;
        __syncthreads();
    }
    bsum[t] = s[t] - v;
}

__global__ void k_scanC(int* __restrict__ rowstart, const int* __restrict__ bsum) {
    int t = threadIdx.x;
    int i = blockIdx.x * 256 + t;
    rowstart[i] += bsum[blockIdx.x];
    if (i == 0) rowstart[NN] = NE;
}

__global__ void k_fill(const int* __restrict__ src, const int* __restrict__ dst,
                       const int* __restrict__ rowstart, int* __restrict__ cursor,
                       const float* __restrict__ dis,
                       int* __restrict__ col, float* __restrict__ wgt) {
    int e = blockIdx.x * blockDim.x + threadIdx.x;
    if (e >= NE) return;
    int s = src[e], d = dst[e];
    int pos = rowstart[d] + atomicAdd(&cursor[d], 1);
    col[pos] = s;
    wgt[pos] = dis[s] * dis[d];
}

// W3 [156][312] fp32 -> W3T [312][KP] bf16 (transposed, zero-padded K)
__global__ void k_prepW(const float* __restrict__ W, ushort* __restrict__ WT) {
    int idx = blockIdx.x * 256 + threadIdx.x;
    if (idx >= 312 * KP) return;
    int n = idx / KP, k = idx - n * KP;
    float v = (k < 156) ? W[k * 312 + n] : 0.0f;
    WT[idx] = f2bf(v);
}

// ---------------- aggregation: out[i] = dis[i]^2*h[i] + sum_e norm*h[src] ----------------

template<int C>
__global__ __launch_bounds__(256)
void k_agg(const float* __restrict__ hin, const int* __restrict__ rowstart,
           const int* __restrict__ col, const float* __restrict__ wgt,
           const float* __restrict__ dis, float* __restrict__ out) {
    const int total = NN * C;
    for (int idx = blockIdx.x * 256 + threadIdx.x; idx < total; idx += gridDim.x * 256) {
        int i = idx / C;
        int c = idx - i * C;
        float d = dis[i];
        float acc = d * d * hin[i * C + c];
        int j1 = rowstart[i + 1];
        for (int j = rowstart[i]; j < j1; ++j) {
            acc = fmaf(wgt[j], hin[col[j] * C + c], acc);
        }
        out[idx] = acc;
    }
}

// same, but bf16 output with zero-padded channels [NN][CP]
template<int C, int CP>
__global__ __launch_bounds__(256)
void k_agg_bf16(const float* __restrict__ hin, const int* __restrict__ rowstart,
                const int* __restrict__ col, const float* __restrict__ wgt,
                const float* __restrict__ dis, ushort* __restrict__ out) {
    const int total = NN * CP;
    for (int idx = blockIdx.x * 256 + threadIdx.x; idx < total; idx += gridDim.x * 256) {
        int i = idx / CP;
        int c = idx - i * CP;
        if (c >= C) { out[idx] = 0; continue; }
        float d = dis[i];
        float acc = d * d * hin[i * C + c];
        int j1 = rowstart[i + 1];
        for (int j = rowstart[i]; j < j1; ++j) {
            acc = fmaf(wgt[j], hin[col[j] * C + c], acc);
        }
        out[idx] = f2bf(acc);
    }
}

// ---------------- layer-3: bf16 MFMA GEMM + fused relu + segment-max pool ----------------
// A [NN][KP] bf16, BT [312][KP] bf16 (W3^T). Tile 64x64, 4 waves (2x2), K=160 in 5 steps.

__global__ __launch_bounds__(256)
void k_mfma_pool(const ushort* __restrict__ A, const ushort* __restrict__ BT,
                 const float* __restrict__ bias, const int* __restrict__ batch,
                 float* __restrict__ pooled) {
    __shared__ ushort sA[64 * LDSROW];
    __shared__ ushort sB[64 * LDSROW];

    const int tid  = threadIdx.x;
    const int row0 = blockIdx.y * 64;
    const int col0 = blockIdx.x * 64;

    // stage A-tile (64 x 160 bf16 = 64 rows x 20 int4-chunks) and B-tile likewise
    #pragma unroll
    for (int p = 0; p < 5; ++p) {
        int id = p * 256 + tid;          // 0..1279
        int r  = id / 20;
        int kc = id - r * 20;
        int4 va = ((const int4*)(A + (size_t)(row0 + r) * KP))[kc];
        ((int4*)(sA + r * LDSROW))[kc] = va;
        int4 vb = {0, 0, 0, 0};
        int bc = col0 + r;
        if (bc < 312) vb = ((const int4*)(BT + (size_t)bc * KP))[kc];
        ((int4*)(sB + r * LDSROW))[kc] = vb;
    }
    __syncthreads();

    const int lane = tid & 63;
    const int wave = tid >> 6;
    const int wr = wave >> 1, wc = wave & 1;
    const int l15 = lane & 15, l4 = lane >> 4;

    f32x4 acc[2][2] = {};
    const ushort* pa0 = sA + (wr * 32 + l15) * LDSROW + l4 * 8;
    const ushort* pb0 = sB + (wc * 32 + l15) * LDSROW + l4 * 8;

    #pragma unroll
    for (int ks = 0; ks < 5; ++ks) {
        bfx8 a0 = *(const bfx8*)(pa0 + ks * 32);
        bfx8 a1 = *(const bfx8*)(pa0 + 16 * LDSROW + ks * 32);
        bfx8 b0 = *(const bfx8*)(pb0 + ks * 32);
        bfx8 b1 = *(const bfx8*)(pb0 + 16 * LDSROW + ks * 32);
        acc[0][0] = __builtin_amdgcn_mfma_f32_16x16x32_bf16(a0, b0, acc[0][0], 0, 0, 0);
        acc[0][1] = __builtin_amdgcn_mfma_f32_16x16x32_bf16(a0, b1, acc[0][1], 0, 0, 0);
        acc[1][0] = __builtin_amdgcn_mfma_f32_16x16x32_bf16(a1, b0, acc[1][0], 0, 0, 0);
        acc[1][1] = __builtin_amdgcn_mfma_f32_16x16x32_bf16(a1, b1, acc[1][1], 0, 0, 0);
    }

    // epilogue: D-frag lane l holds rows (l>>4)*4+j (within 16) at col l&15.
    // wave's 32 rows = one aligned graph group (32 nodes/graph) in the uniform case.
    const int gbase = row0 + wr * 32;
    const bool uni = (batch[gbase] == batch[gbase + 31]);

    #pragma unroll
    for (int fn = 0; fn < 2; ++fn) {
        int cg = col0 + wc * 32 + fn * 16 + l15;
        bool cok = cg < 312;
        float bs = cok ? bias[cg] : 0.0f;
        if (uni) {
            float m = -1e30f;
            #pragma unroll
            for (int fm = 0; fm < 2; ++fm)
                #pragma unroll
                for (int j = 0; j < 4; ++j)
                    m = fmaxf(m, acc[fm][fn][j]);
            m = fmaxf(m, __shfl_xor(m, 16));
            m = fmaxf(m, __shfl_xor(m, 32));
            if (l4 == 0 && cok) {
                int g = batch[gbase];
                float v = fmaxf(m + bs, 0.0f);
                atomicMax((int*)&pooled[g * 312 + cg], __float_as_int(v));
            }
        } else {
            #pragma unroll
            for (int fm = 0; fm < 2; ++fm)
                #pragma unroll
                for (int j = 0; j < 4; ++j) {
                    if (cok) {
                        int rg = gbase + fm * 16 + l4 * 4 + j;
                        int g = batch[rg];
                        float v = fmaxf(acc[fm][fn][j] + bs, 0.0f);
                        atomicMax((int*)&pooled[g * 312 + cg], __float_as_int(v));
                    }
                }
        }
    }
}

// ---------------- fp32 GEMM: out = relu?(A @ W + b) ----------------

template<int CI, int CO, bool RELU>
__global__ __launch_bounds__(256)
void k_gemm(const float* __restrict__ A, const float* __restrict__ Wm,
            const float* __restrict__ bias, float* __restrict__ out) {
    __shared__ float sA[8][68];
    __shared__ float sB[8][68];

    const int tid = threadIdx.x;
    const int tx = tid & 15;
    const int ty = tid >> 4;
    const int row0 = blockIdx.y * 64;
    const int col0 = blockIdx.x * 64;

    float acc[4][4] = {};

    const int la_k = tid & 7;
    const int la_m = tid >> 3;
    const int lb_c = tid & 63;
    const int lb_k = tid >> 6;

    for (int k0 = 0; k0 < CI; k0 += 8) {
        #pragma unroll
        for (int mm = la_m; mm < 64; mm += 32) {
            float v = 0.0f;
            if (k0 + la_k < CI) v = A[(row0 + mm) * CI + k0 + la_k];
            sA[la_k][mm] = v;
        }
        #pragma unroll
        for (int kk = lb_k; kk < 8; kk += 4) {
            float v = 0.0f;
            int col = col0 + lb_c;
            if (k0 + kk < CI && col < CO) v = Wm[(k0 + kk) * CO + col];
            sB[kk][lb_c] = v;
        }
        __syncthreads();
        #pragma unroll
        for (int kk = 0; kk < 8; ++kk) {
            float ra[4], rb[4];
            #pragma unroll
            for (int i = 0; i < 4; ++i) ra[i] = sA[kk][ty * 4 + i];
            #pragma unroll
            for (int j = 0; j < 4; ++j) rb[j] = sB[kk][tx * 4 + j];
            #pragma unroll
            for (int i = 0; i < 4; ++i)
                #pragma unroll
                for (int j = 0; j < 4; ++j)
                    acc[i][j] = fmaf(ra[i], rb[j], acc[i][j]);
        }
        __syncthreads();
    }

    #pragma unroll
    for (int i = 0; i < 4; ++i) {
        int row = row0 + ty * 4 + i;
        #pragma unroll
        for (int j = 0; j < 4; ++j) {
            int col = col0 + tx * 4 + j;
            if (col < CO) {
                float v = acc[i][j] + bias[col];
                if (RELU) v = fmaxf(v, 0.0f);
                out[row * CO + col] = v;
            }
        }
    }
}

// ---------------- launch ----------------

extern "C" void kernel_launch(void* const* d_in, const int* in_sizes, int n_in,
                              void* d_out, int out_size, void* d_ws, size_t ws_size,
                              hipStream_t stream) {
    const float* x    = (const float*)d_in[0];
    const int*   ei   = (const int*)d_in[1];
    const int*   srcv = ei;
    const int*   dstv = ei + NE;
    const int*   batch = (const int*)d_in[2];
    const float* W1 = (const float*)d_in[3];
    const float* b1 = (const float*)d_in[4];
    const float* W2 = (const float*)d_in[5];
    const float* b2 = (const float*)d_in[6];
    const float* W3 = (const float*)d_in[7];
    const float* b3 = (const float*)d_in[8];
    const float* fcW = (const float*)d_in[9];
    const float* fcb = (const float*)d_in[10];
    float* out = (float*)d_out;

    char* ws = (char*)d_ws;
    size_t off = 0;
    auto take = [&](size_t bytes) -> void* {
        void* p = ws + off;
        off += (bytes + 255) & ~(size_t)255;
        return p;
    };
    int*    counts   = (int*)take((size_t)NN * 4);
    int*    rowstart = (int*)take((size_t)(NN + 1) * 4);
    int*    cursor   = (int*)take((size_t)NN * 4);
    float*  dis      = (float*)take((size_t)NN * 4);
    int*    bsum     = (int*)take(512 * 4);
    int*    col      = (int*)take((size_t)NE * 4);
    float*  wgt      = (float*)take((size_t)NE * 4);
    float*  B0       = (float*)take((size_t)NN * 156 * 4);
    float*  B1       = (float*)take((size_t)NN * 156 * 4);
    float*  pooled   = (float*)take((size_t)NG * 312 * 4);
    ushort* W3T      = (ushort*)take((size_t)312 * KP * 2);
    ushort* A3       = (ushort*)B0;   // alias: layer-3 bf16 agg output reuses B0 (42 MB < 82 MB)

    hipMemsetAsync(counts, 0, (size_t)NN * 4, stream);
    hipMemsetAsync(cursor, 0, (size_t)NN * 4, stream);
    hipMemsetAsync(pooled, 0, (size_t)NG * 312 * 4, stream);

    k_count<<<NE / 256, 256, 0, stream>>>(dstv, counts);
    k_dis<<<NN / 256, 256, 0, stream>>>(counts, dis);
    k_scanA<<<NN / 256, 256, 0, stream>>>(counts, rowstart, bsum);
    k_scanB<<<1, 512, 0, stream>>>(bsum);
    k_scanC<<<NN / 256, 256, 0, stream>>>(rowstart, bsum);
    k_fill<<<NE / 256, 256, 0, stream>>>(srcv, dstv, rowstart, cursor, dis, col, wgt);
    k_prepW<<<(312 * KP + 255) / 256, 256, 0, stream>>>(W3, W3T);

    // layer 1: agg(x) -> B0 ; relu(B0@W1+b1) -> B1
    k_agg<78><<<2048, 256, 0, stream>>>(x, rowstart, col, wgt, dis, B0);
    k_gemm<78, 78, true><<<dim3(2, NN / 64), 256, 0, stream>>>(B0, W1, b1, B1);
    // layer 2: agg(B1) -> B0 ; relu(B0@W2+b2) -> B1
    k_agg<78><<<2048, 256, 0, stream>>>(B1, rowstart, col, wgt, dis, B0);
    k_gemm<78, 156, true><<<dim3(3, NN / 64), 256, 0, stream>>>(B0, W2, b2, B1);
    // layer 3: agg(B1) -> A3 (bf16, K-padded) ; MFMA gemm + relu + segment-max -> pooled
    k_agg_bf16<156, KP><<<2048, 256, 0, stream>>>(B1, rowstart, col, wgt, dis, A3);
    k_mfma_pool<<<dim3(5, NN / 64), 256, 0, stream>>>(A3, W3T, b3, batch, pooled);
    // FC: pooled @ fcW + fcb -> out
    k_gemm<312, 128, false><<<dim3(2, NG / 64), 256, 0, stream>>>(pooled, fcW, fcb, out);
}

// Round 6
// 434.196 us; speedup vs baseline: 2.1411x; 1.7229x over previous
//
#include <hip/hip_runtime.h>

#define NN 131072   // nodes
#define NE 524288   // edges
#define NG 4096     // graphs

typedef __attribute__((ext_vector_type(8))) short bfx8;
typedef __attribute__((ext_vector_type(4))) float f32x4;

static __device__ __forceinline__ ushort f2bf(float f) {
    union { float f; unsigned u; } v; v.f = f;
    unsigned r = (v.u + 0x7fff + ((v.u >> 16) & 1)) >> 16;   // RNE
    return (ushort)r;
}
static __device__ __forceinline__ float bf2f(short s) {
    union { unsigned u; float f; } v;
    v.u = ((unsigned)(ushort)s) << 16;
    return v.f;
}

// ---------------- preprocessing: degree, dis, CSR ----------------

__global__ void k_count(const int* __restrict__ dst, int* __restrict__ counts) {
    int e = blockIdx.x * blockDim.x + threadIdx.x;
    if (e < NE) atomicAdd(&counts[dst[e]], 1);
}

__global__ void k_dis(const int* __restrict__ counts, float* __restrict__ dis) {
    int i = blockIdx.x * blockDim.x + threadIdx.x;
    if (i < NN) dis[i] = rsqrtf((float)(counts[i] + 1));  // +1 self-loop
}

__global__ void k_scanA(const int* __restrict__ in, int* __restrict__ out, int* __restrict__ bsum) {
    __shared__ int s[256];
    int t = threadIdx.x;
    int i = blockIdx.x * 256 + t;
    int v = in[i];
    s[t] = v;
    __syncthreads();
    for (int off = 1; off < 256; off <<= 1) {
        int x = (t >= off) ? s[t - off] : 0;
        __syncthreads();
        s[t] += x;
        __syncthreads();
    }
    out[i] = s[t] - v;
    if (t == 255) bsum[blockIdx.x] = s[t];
}

__global__ void k_scanB(int* __restrict__ bsum) {
    __shared__ int s[512];
    int t = threadIdx.x;
    int v = bsum[t];
    s[t] = v;
    __syncthreads();
    for (int off = 1; off < 512; off <<= 1) {
        int x = (t >= off) ? s[t - off] : 0;
        __syncthreads();
        s[t] += x;
        __syncthreads();
    }
    bsum[t] = s[t] - v;
}

__global__ void k_scanC(int* __restrict__ rowstart, const int* __restrict__ bsum) {
    int t = threadIdx.x;
    int i = blockIdx.x * 256 + t;
    rowstart[i] += bsum[blockIdx.x];
    if (i == 0) rowstart[NN] = NE;
}

__global__ void k_fill(const int* __restrict__ src, const int* __restrict__ dst,
                       const int* __restrict__ rowstart, int* __restrict__ cursor,
                       const float* __restrict__ dis,
                       int* __restrict__ col, float* __restrict__ wgt) {
    int e = blockIdx.x * blockDim.x + threadIdx.x;
    if (e >= NE) return;
    int s = src[e], d = dst[e];
    int pos = rowstart[d] + atomicAdd(&cursor[d], 1);
    col[pos] = s;
    wgt[pos] = dis[s] * dis[d];
}

// W [CI][CO] fp32 -> WT [CO][KP] bf16 (transposed, zero-padded K)
template<int CI, int CO, int KP>
__global__ void k_prepW(const float* __restrict__ W, ushort* __restrict__ WT) {
    int idx = blockIdx.x * 256 + threadIdx.x;
    if (idx >= CO * KP) return;
    int n = idx / KP, k = idx - n * KP;
    float v = (k < CI) ? W[k * CO + n] : 0.0f;
    WT[idx] = f2bf(v);
}

// x [NN][78] fp32 -> xb [NN][96] bf16 zero-padded
__global__ void k_prepX(const float* __restrict__ x, ushort* __restrict__ xb) {
    int idx = blockIdx.x * 256 + threadIdx.x;   // exact NN*96
    int i = idx / 96, c = idx - i * 96;
    xb[idx] = (c < 78) ? f2bf(x[i * 78 + c]) : (ushort)0;
}

// ---------------- aggregation (bf16 in/out, fp32 accum) ----------------
// out[i,:] = dis[i]^2 * h[i,:] + sum_edges wgt * h[col,:]
// thread = (node, 8-channel chunk); edge loop batched x4 to break the
// col->gather dependent chain (expose MLP).

template<int CP>
__global__ __launch_bounds__(256)
void k_agg8(const ushort* __restrict__ hin, const int* __restrict__ rowstart,
            const int* __restrict__ col, const float* __restrict__ wgt,
            const float* __restrict__ dis, ushort* __restrict__ out) {
    constexpr int CH = CP / 8;
    int idx = blockIdx.x * 256 + threadIdx.x;   // exact NN*CH threads
    int i = idx / CH;
    int ch = (idx - i * CH) * 8;
    const ushort* base = hin + ch;

    float d = dis[i];
    bfx8 self = *(const bfx8*)(hin + (size_t)i * CP + ch);
    float acc[8];
    #pragma unroll
    for (int k = 0; k < 8; ++k) acc[k] = d * d * bf2f(self[k]);

    int j = rowstart[i], j1 = rowstart[i + 1];
    for (; j + 4 <= j1; j += 4) {
        int c0 = col[j], c1 = col[j + 1], c2 = col[j + 2], c3 = col[j + 3];
        float w0 = wgt[j], w1 = wgt[j + 1], w2 = wgt[j + 2], w3 = wgt[j + 3];
        bfx8 g0 = *(const bfx8*)(base + (size_t)c0 * CP);
        bfx8 g1 = *(const bfx8*)(base + (size_t)c1 * CP);
        bfx8 g2 = *(const bfx8*)(base + (size_t)c2 * CP);
        bfx8 g3 = *(const bfx8*)(base + (size_t)c3 * CP);
        #pragma unroll
        for (int k = 0; k < 8; ++k) {
            acc[k] = fmaf(w0, bf2f(g0[k]), acc[k]);
            acc[k] = fmaf(w1, bf2f(g1[k]), acc[k]);
            acc[k] = fmaf(w2, bf2f(g2[k]), acc[k]);
            acc[k] = fmaf(w3, bf2f(g3[k]), acc[k]);
        }
    }
    for (; j < j1; ++j) {
        int c = col[j];
        float w = wgt[j];
        bfx8 g = *(const bfx8*)(base + (size_t)c * CP);
        #pragma unroll
        for (int k = 0; k < 8; ++k) acc[k] = fmaf(w, bf2f(g[k]), acc[k]);
    }

    bfx8 ov;
    #pragma unroll
    for (int k = 0; k < 8; ++k) ov[k] = (short)f2bf(acc[k]);
    *(bfx8*)(out + (size_t)i * CP + ch) = ov;
}

// ---------------- bf16 MFMA GEMM: relu(A@W+b), bf16 out or fused segment-max pool ----
// A [NN][KP] bf16, BT [CO][KP] bf16. Tile 64x64, 4 waves (2x2 of 32x32).

template<int KP, int LROW, int CO, int CPO, bool POOL>
__global__ __launch_bounds__(256)
void k_mfma(const ushort* __restrict__ A, const ushort* __restrict__ BT,
            const float* __restrict__ bias, const int* __restrict__ batch,
            ushort* __restrict__ hout, float* __restrict__ pooled) {
    constexpr int NCH = KP / 8;           // int4 chunks per row
    __shared__ ushort sA[64 * LROW];
    __shared__ ushort sB[64 * LROW];

    const int tid  = threadIdx.x;
    const int row0 = blockIdx.y * 64;
    const int col0 = blockIdx.x * 64;

    for (int id = tid; id < 64 * NCH; id += 256) {
        int r = id / NCH, kc = id - r * NCH;
        ((int4*)(sA + r * LROW))[kc] = ((const int4*)(A + (size_t)(row0 + r) * KP))[kc];
        int4 vb = {0, 0, 0, 0};
        int bc = col0 + r;
        if (bc < CO) vb = ((const int4*)(BT + (size_t)bc * KP))[kc];
        ((int4*)(sB + r * LROW))[kc] = vb;
    }
    __syncthreads();

    const int lane = tid & 63;
    const int wave = tid >> 6;
    const int wr = wave >> 1, wc = wave & 1;
    const int l15 = lane & 15, l4 = lane >> 4;

    f32x4 acc[2][2] = {};
    const ushort* pa0 = sA + (wr * 32 + l15) * LROW + l4 * 8;
    const ushort* pb0 = sB + (wc * 32 + l15) * LROW + l4 * 8;

    #pragma unroll
    for (int ks = 0; ks < KP / 32; ++ks) {
        bfx8 a0 = *(const bfx8*)(pa0 + ks * 32);
        bfx8 a1 = *(const bfx8*)(pa0 + 16 * LROW + ks * 32);
        bfx8 b0 = *(const bfx8*)(pb0 + ks * 32);
        bfx8 b1 = *(const bfx8*)(pb0 + 16 * LROW + ks * 32);
        acc[0][0] = __builtin_amdgcn_mfma_f32_16x16x32_bf16(a0, b0, acc[0][0], 0, 0, 0);
        acc[0][1] = __builtin_amdgcn_mfma_f32_16x16x32_bf16(a0, b1, acc[0][1], 0, 0, 0);
        acc[1][0] = __builtin_amdgcn_mfma_f32_16x16x32_bf16(a1, b0, acc[1][0], 0, 0, 0);
        acc[1][1] = __builtin_amdgcn_mfma_f32_16x16x32_bf16(a1, b1, acc[1][1], 0, 0, 0);
    }

    // D-frag: lane l holds (row = fm*16 + (l>>4)*4 + j, col = fn*16 + (l&15)) of wave's 32x32.
    const int gbase = row0 + wr * 32;

    if constexpr (POOL) {
        const bool uni = (batch[gbase] == batch[gbase + 31]);
        #pragma unroll
        for (int fn = 0; fn < 2; ++fn) {
            int cg = col0 + wc * 32 + fn * 16 + l15;
            bool cok = cg < CO;
            float bs = cok ? bias[cg] : 0.0f;
            if (uni) {
                float m = -1e30f;
                #pragma unroll
                for (int fm = 0; fm < 2; ++fm)
                    #pragma unroll
                    for (int j = 0; j < 4; ++j)
                        m = fmaxf(m, acc[fm][fn][j]);
                m = fmaxf(m, __shfl_xor(m, 16));
                m = fmaxf(m, __shfl_xor(m, 32));
                if (l4 == 0 && cok) {
                    int g = batch[gbase];
                    float v = fmaxf(m + bs, 0.0f);
                    atomicMax((int*)&pooled[g * CO + cg], __float_as_int(v));
                }
            } else {
                #pragma unroll
                for (int fm = 0; fm < 2; ++fm)
                    #pragma unroll
                    for (int j = 0; j < 4; ++j) {
                        if (cok) {
                            int rg = gbase + fm * 16 + l4 * 4 + j;
                            int g = batch[rg];
                            float v = fmaxf(acc[fm][fn][j] + bs, 0.0f);
                            atomicMax((int*)&pooled[g * CO + cg], __float_as_int(v));
                        }
                    }
            }
        }
    } else {
        #pragma unroll
        for (int fn = 0; fn < 2; ++fn) {
            int cg = col0 + wc * 32 + fn * 16 + l15;
            if (cg >= CPO) continue;
            float bs = (cg < CO) ? bias[cg] : 0.0f;
            #pragma unroll
            for (int fm = 0; fm < 2; ++fm)
                #pragma unroll
                for (int j = 0; j < 4; ++j) {
                    int row = gbase + fm * 16 + l4 * 4 + j;
                    float v = (cg < CO) ? fmaxf(acc[fm][fn][j] + bs, 0.0f) : 0.0f;
                    hout[(size_t)row * CPO + cg] = f2bf(v);
                }
        }
    }
}

// ---------------- fp32 GEMM for the final FC ----------------

template<int CI, int CO, bool RELU>
__global__ __launch_bounds__(256)
void k_gemm(const float* __restrict__ A, const float* __restrict__ Wm,
            const float* __restrict__ bias, float* __restrict__ out) {
    __shared__ float sA[8][68];
    __shared__ float sB[8][68];

    const int tid = threadIdx.x;
    const int tx = tid & 15;
    const int ty = tid >> 4;
    const int row0 = blockIdx.y * 64;
    const int col0 = blockIdx.x * 64;

    float acc[4][4] = {};

    const int la_k = tid & 7;
    const int la_m = tid >> 3;
    const int lb_c = tid & 63;
    const int lb_k = tid >> 6;

    for (int k0 = 0; k0 < CI; k0 += 8) {
        #pragma unroll
        for (int mm = la_m; mm < 64; mm += 32) {
            float v = 0.0f;
            if (k0 + la_k < CI) v = A[(row0 + mm) * CI + k0 + la_k];
            sA[la_k][mm] = v;
        }
        #pragma unroll
        for (int kk = lb_k; kk < 8; kk += 4) {
            float v = 0.0f;
            int c = col0 + lb_c;
            if (k0 + kk < CI && c < CO) v = Wm[(k0 + kk) * CO + c];
            sB[kk][lb_c] = v;
        }
        __syncthreads();
        #pragma unroll
        for (int kk = 0; kk < 8; ++kk) {
            float ra[4], rb[4];
            #pragma unroll
            for (int i = 0; i < 4; ++i) ra[i] = sA[kk][ty * 4 + i];
            #pragma unroll
            for (int j = 0; j < 4; ++j) rb[j] = sB[kk][tx * 4 + j];
            #pragma unroll
            for (int i = 0; i < 4; ++i)
                #pragma unroll
                for (int j = 0; j < 4; ++j)
                    acc[i][j] = fmaf(ra[i], rb[j], acc[i][j]);
        }
        __syncthreads();
    }

    #pragma unroll
    for (int i = 0; i < 4; ++i) {
        int row = row0 + ty * 4 + i;
        #pragma unroll
        for (int j = 0; j < 4; ++j) {
            int c = col0 + tx * 4 + j;
            if (c < CO) {
                float v = acc[i][j] + bias[c];
                if (RELU) v = fmaxf(v, 0.0f);
                out[row * CO + c] = v;
            }
        }
    }
}

// ---------------- launch ----------------

extern "C" void kernel_launch(void* const* d_in, const int* in_sizes, int n_in,
                              void* d_out, int out_size, void* d_ws, size_t ws_size,
                              hipStream_t stream) {
    const float* x    = (const float*)d_in[0];
    const int*   ei   = (const int*)d_in[1];
    const int*   srcv = ei;
    const int*   dstv = ei + NE;
    const int*   batch = (const int*)d_in[2];
    const float* W1 = (const float*)d_in[3];
    const float* b1 = (const float*)d_in[4];
    const float* W2 = (const float*)d_in[5];
    const float* b2 = (const float*)d_in[6];
    const float* W3 = (const float*)d_in[7];
    const float* b3 = (const float*)d_in[8];
    const float* fcW = (const float*)d_in[9];
    const float* fcb = (const float*)d_in[10];
    float* out = (float*)d_out;

    char* ws = (char*)d_ws;
    size_t off = 0;
    auto take = [&](size_t bytes) -> void* {
        void* p = ws + off;
        off += (bytes + 255) & ~(size_t)255;
        return p;
    };
    int*    counts   = (int*)take((size_t)NN * 4);
    int*    rowstart = (int*)take((size_t)(NN + 1) * 4);
    int*    cursor   = (int*)take((size_t)NN * 4);
    float*  dis      = (float*)take((size_t)NN * 4);
    int*    bsum     = (int*)take(512 * 4);
    int*    col      = (int*)take((size_t)NE * 4);
    float*  wgt      = (float*)take((size_t)NE * 4);
    ushort* R1       = (ushort*)take((size_t)NN * 160 * 2);  // xb / A2 / A3
    ushort* R2       = (ushort*)take((size_t)NN * 160 * 2);  // A1 / h2
    ushort* R3       = (ushort*)take((size_t)NN * 96 * 2);   // h1
    float*  pooled   = (float*)take((size_t)NG * 312 * 4);
    ushort* W1T      = (ushort*)take((size_t)78 * 96 * 2);
    ushort* W2T      = (ushort*)take((size_t)156 * 96 * 2);
    ushort* W3T      = (ushort*)take((size_t)312 * 160 * 2);

    ushort* xb = R1;   // [NN][96]
    ushort* A1 = R2;   // [NN][96]
    ushort* h1 = R3;   // [NN][96]
    ushort* A2 = R1;   // [NN][96]  (xb dead)
    ushort* h2 = R2;   // [NN][160] (A1 dead)
    ushort* A3 = R1;   // [NN][160] (A2 dead)

    hipMemsetAsync(counts, 0, (size_t)NN * 4, stream);
    hipMemsetAsync(cursor, 0, (size_t)NN * 4, stream);
    hipMemsetAsync(pooled, 0, (size_t)NG * 312 * 4, stream);

    k_count<<<NE / 256, 256, 0, stream>>>(dstv, counts);
    k_dis<<<NN / 256, 256, 0, stream>>>(counts, dis);
    k_scanA<<<NN / 256, 256, 0, stream>>>(counts, rowstart, bsum);
    k_scanB<<<1, 512, 0, stream>>>(bsum);
    k_scanC<<<NN / 256, 256, 0, stream>>>(rowstart, bsum);
    k_fill<<<NE / 256, 256, 0, stream>>>(srcv, dstv, rowstart, cursor, dis, col, wgt);

    k_prepW<78, 78, 96><<<(78 * 96 + 255) / 256, 256, 0, stream>>>(W1, W1T);
    k_prepW<78, 156, 96><<<(156 * 96 + 255) / 256, 256, 0, stream>>>(W2, W2T);
    k_prepW<156, 312, 160><<<(312 * 160 + 255) / 256, 256, 0, stream>>>(W3, W3T);
    k_prepX<<<NN * 96 / 256, 256, 0, stream>>>(x, xb);

    // layer 1
    k_agg8<96><<<NN * 12 / 256, 256, 0, stream>>>(xb, rowstart, col, wgt, dis, A1);
    k_mfma<96, 104, 78, 96, false><<<dim3(2, NN / 64), 256, 0, stream>>>(A1, W1T, b1, nullptr, h1, nullptr);
    // layer 2
    k_agg8<96><<<NN * 12 / 256, 256, 0, stream>>>(h1, rowstart, col, wgt, dis, A2);
    k_mfma<96, 104, 156, 160, false><<<dim3(3, NN / 64), 256, 0, stream>>>(A2, W2T, b2, nullptr, h2, nullptr);
    // layer 3 + pool
    k_agg8<160><<<NN * 20 / 256, 256, 0, stream>>>(h2, rowstart, col, wgt, dis, A3);
    k_mfma<160, 168, 312, 312, true><<<dim3(5, NN / 64), 256, 0, stream>>>(A3, W3T, b3, batch, nullptr, pooled);
    // FC (fp32)
    k_gemm<312, 128, false><<<dim3(2, NG / 64), 256, 0, stream>>>(pooled, fcW, fcb, out);
}

// Round 7
// 417.509 us; speedup vs baseline: 2.2267x; 1.0400x over previous
//
#include <hip/hip_runtime.h>

#define NN 131072   // nodes
#define NE 524288   // edges
#define NG 4096     // graphs

typedef __attribute__((ext_vector_type(8))) short bfx8;
typedef __attribute__((ext_vector_type(4))) float f32x4;

static __device__ __forceinline__ ushort f2bf(float f) {
    union { float f; unsigned u; } v; v.f = f;
    unsigned r = (v.u + 0x7fff + ((v.u >> 16) & 1)) >> 16;   // RNE
    return (ushort)r;
}
static __device__ __forceinline__ float bf2f(short s) {
    union { unsigned u; float f; } v;
    v.u = ((unsigned)(ushort)s) << 16;
    return v.f;
}

// ---------------- preprocessing: degree, dis, CSR ----------------

__global__ void k_count(const int* __restrict__ dst, int* __restrict__ counts) {
    int e = blockIdx.x * blockDim.x + threadIdx.x;
    if (e < NE) atomicAdd(&counts[dst[e]], 1);
}

__global__ void k_dis(const int* __restrict__ counts, float* __restrict__ dis) {
    int i = blockIdx.x * blockDim.x + threadIdx.x;
    if (i < NN) dis[i] = rsqrtf((float)(counts[i] + 1));  // +1 self-loop
}

__global__ void k_scanA(const int* __restrict__ in, int* __restrict__ out, int* __restrict__ bsum) {
    __shared__ int s[256];
    int t = threadIdx.x;
    int i = blockIdx.x * 256 + t;
    int v = in[i];
    s[t] = v;
    __syncthreads();
    for (int off = 1; off < 256; off <<= 1) {
        int x = (t >= off) ? s[t - off] : 0;
        __syncthreads();
        s[t] += x;
        __syncthreads();
    }
    out[i] = s[t] - v;
    if (t == 255) bsum[blockIdx.x] = s[t];
}

__global__ void k_scanB(int* __restrict__ bsum) {
    __shared__ int s[512];
    int t = threadIdx.x;
    int v = bsum[t];
    s[t] = v;
    __syncthreads();
    for (int off = 1; off < 512; off <<= 1) {
        int x = (t >= off) ? s[t - off] : 0;
        __syncthreads();
        s[t] += x;
        __syncthreads();
    }
    bsum[t] = s[t] - v;
}

__global__ void k_scanC(int* __restrict__ rowstart, const int* __restrict__ bsum) {
    int t = threadIdx.x;
    int i = blockIdx.x * 256 + t;
    rowstart[i] += bsum[blockIdx.x];
    if (i == 0) rowstart[NN] = NE;
}

__global__ void k_fill(const int* __restrict__ src, const int* __restrict__ dst,
                       const int* __restrict__ rowstart, int* __restrict__ cursor,
                       const float* __restrict__ dis,
                       int* __restrict__ col, float* __restrict__ wgt) {
    int e = blockIdx.x * blockDim.x + threadIdx.x;
    if (e >= NE) return;
    int s = src[e], d = dst[e];
    int pos = rowstart[d] + atomicAdd(&cursor[d], 1);
    col[pos] = s;
    wgt[pos] = dis[s] * dis[d];
}

// W [CI][CO] fp32 -> WT [CO][KP] bf16 (transposed, zero-padded K)
template<int CI, int CO, int KP>
__global__ void k_prepW(const float* __restrict__ W, ushort* __restrict__ WT) {
    int idx = blockIdx.x * 256 + threadIdx.x;
    if (idx >= CO * KP) return;
    int n = idx / KP, k = idx - n * KP;
    float v = (k < CI) ? W[k * CO + n] : 0.0f;
    WT[idx] = f2bf(v);
}

// x [NN][78] fp32 -> xb [NN][96] bf16 zero-padded
__global__ void k_prepX(const float* __restrict__ x, ushort* __restrict__ xb) {
    int idx = blockIdx.x * 256 + threadIdx.x;   // exact NN*96
    int i = idx / 96, c = idx - i * 96;
    xb[idx] = (c < 78) ? f2bf(x[i * 78 + c]) : (ushort)0;
}

// ---------------- aggregation (bf16 in/out, fp32 accum) ----------------

template<int CP>
__global__ __launch_bounds__(256)
void k_agg8(const ushort* __restrict__ hin, const int* __restrict__ rowstart,
            const int* __restrict__ col, const float* __restrict__ wgt,
            const float* __restrict__ dis, ushort* __restrict__ out) {
    constexpr int CH = CP / 8;
    int idx = blockIdx.x * 256 + threadIdx.x;   // exact NN*CH threads
    int i = idx / CH;
    int ch = (idx - i * CH) * 8;
    const ushort* base = hin + ch;

    float d = dis[i];
    bfx8 self = *(const bfx8*)(hin + (size_t)i * CP + ch);
    float acc[8];
    #pragma unroll
    for (int k = 0; k < 8; ++k) acc[k] = d * d * bf2f(self[k]);

    int j = rowstart[i], j1 = rowstart[i + 1];
    for (; j + 4 <= j1; j += 4) {
        int c0 = col[j], c1 = col[j + 1], c2 = col[j + 2], c3 = col[j + 3];
        float w0 = wgt[j], w1 = wgt[j + 1], w2 = wgt[j + 2], w3 = wgt[j + 3];
        bfx8 g0 = *(const bfx8*)(base + (size_t)c0 * CP);
        bfx8 g1 = *(const bfx8*)(base + (size_t)c1 * CP);
        bfx8 g2 = *(const bfx8*)(base + (size_t)c2 * CP);
        bfx8 g3 = *(const bfx8*)(base + (size_t)c3 * CP);
        #pragma unroll
        for (int k = 0; k < 8; ++k) {
            acc[k] = fmaf(w0, bf2f(g0[k]), acc[k]);
            acc[k] = fmaf(w1, bf2f(g1[k]), acc[k]);
            acc[k] = fmaf(w2, bf2f(g2[k]), acc[k]);
            acc[k] = fmaf(w3, bf2f(g3[k]), acc[k]);
        }
    }
    for (; j < j1; ++j) {
        int c = col[j];
        float w = wgt[j];
        bfx8 g = *(const bfx8*)(base + (size_t)c * CP);
        #pragma unroll
        for (int k = 0; k < 8; ++k) acc[k] = fmaf(w, bf2f(g[k]), acc[k]);
    }

    bfx8 ov;
    #pragma unroll
    for (int k = 0; k < 8; ++k) ov[k] = (short)f2bf(acc[k]);
    *(bfx8*)(out + (size_t)i * CP + ch) = ov;
}

// ---------------- bf16 MFMA GEMM with T2 XOR-swizzled LDS ----------------
// A [NN][KP] bf16, BT [CO][KP] bf16. Tile 64x64, 4 waves (2x2 of 32x32).
// LDS: row pitch LCH chunks (16B each), LCH = NCH rounded up to mult of 8.
// chunk position = (c & ~7) | ((c & 7) ^ (row & 7))  -- applied on write AND read.

template<int KP, int LCH, int CO, int CPO, bool POOL>
__global__ __launch_bounds__(256)
void k_mfma(const ushort* __restrict__ A, const ushort* __restrict__ BT,
            const float* __restrict__ bias, const int* __restrict__ batch,
            ushort* __restrict__ hout, float* __restrict__ pooled) {
    constexpr int NCH = KP / 8;           // data chunks per row
    constexpr int LP  = LCH * 8;          // LDS row pitch in bf16 elems
    __shared__ ushort sA[64 * LP];
    __shared__ ushort sB[64 * LP];

    const int tid  = threadIdx.x;
    const int row0 = blockIdx.y * 64;
    const int col0 = blockIdx.x * 64;

    for (int id = tid; id < 64 * NCH; id += 256) {
        int r = id / NCH, kc = id - r * NCH;
        int swz = (kc & ~7) | ((kc & 7) ^ (r & 7));
        ((int4*)(sA + r * LP))[swz] = ((const int4*)(A + (size_t)(row0 + r) * KP))[kc];
        int4 vb = {0, 0, 0, 0};
        int bc = col0 + r;
        if (bc < CO) vb = ((const int4*)(BT + (size_t)bc * KP))[kc];
        ((int4*)(sB + r * LP))[swz] = vb;
    }
    __syncthreads();

    const int lane = tid & 63;
    const int wave = tid >> 6;
    const int wr = wave >> 1, wc = wave & 1;
    const int l15 = lane & 15, l4 = lane >> 4;
    const int r7 = l15 & 7;

    f32x4 acc[2][2] = {};
    const int rowA0 = wr * 32 + l15;
    const int rowB0 = wc * 32 + l15;

    #pragma unroll
    for (int ks = 0; ks < KP / 32; ++ks) {
        int chunk = l4 + ks * 4;
        int swz = (chunk & ~7) | ((chunk & 7) ^ r7);
        int off = swz * 8;
        bfx8 a0 = *(const bfx8*)(sA + rowA0 * LP + off);
        bfx8 a1 = *(const bfx8*)(sA + (rowA0 + 16) * LP + off);
        bfx8 b0 = *(const bfx8*)(sB + rowB0 * LP + off);
        bfx8 b1 = *(const bfx8*)(sB + (rowB0 + 16) * LP + off);
        acc[0][0] = __builtin_amdgcn_mfma_f32_16x16x32_bf16(a0, b0, acc[0][0], 0, 0, 0);
        acc[0][1] = __builtin_amdgcn_mfma_f32_16x16x32_bf16(a0, b1, acc[0][1], 0, 0, 0);
        acc[1][0] = __builtin_amdgcn_mfma_f32_16x16x32_bf16(a1, b0, acc[1][0], 0, 0, 0);
        acc[1][1] = __builtin_amdgcn_mfma_f32_16x16x32_bf16(a1, b1, acc[1][1], 0, 0, 0);
    }

    // D-frag: lane l holds (row = fm*16 + (l>>4)*4 + j, col = fn*16 + (l&15)).
    const int gbase = row0 + wr * 32;

    if constexpr (POOL) {
        const bool uni = (batch[gbase] == batch[gbase + 31]);
        #pragma unroll
        for (int fn = 0; fn < 2; ++fn) {
            int cg = col0 + wc * 32 + fn * 16 + l15;
            bool cok = cg < CO;
            float bs = cok ? bias[cg] : 0.0f;
            if (uni) {
                float m = -1e30f;
                #pragma unroll
                for (int fm = 0; fm < 2; ++fm)
                    #pragma unroll
                    for (int j = 0; j < 4; ++j)
                        m = fmaxf(m, acc[fm][fn][j]);
                m = fmaxf(m, __shfl_xor(m, 16));
                m = fmaxf(m, __shfl_xor(m, 32));
                if (l4 == 0 && cok) {
                    int g = batch[gbase];
                    float v = fmaxf(m + bs, 0.0f);
                    atomicMax((int*)&pooled[g * CO + cg], __float_as_int(v));
                }
            } else {
                #pragma unroll
                for (int fm = 0; fm < 2; ++fm)
                    #pragma unroll
                    for (int j = 0; j < 4; ++j) {
                        if (cok) {
                            int rg = gbase + fm * 16 + l4 * 4 + j;
                            int g = batch[rg];
                            float v = fmaxf(acc[fm][fn][j] + bs, 0.0f);
                            atomicMax((int*)&pooled[g * CO + cg], __float_as_int(v));
                        }
                    }
            }
        }
    } else {
        #pragma unroll
        for (int fn = 0; fn < 2; ++fn) {
            int cg = col0 + wc * 32 + fn * 16 + l15;
            if (cg >= CPO) continue;
            float bs = (cg < CO) ? bias[cg] : 0.0f;
            #pragma unroll
            for (int fm = 0; fm < 2; ++fm)
                #pragma unroll
                for (int j = 0; j < 4; ++j) {
                    int row = gbase + fm * 16 + l4 * 4 + j;
                    float v = (cg < CO) ? fmaxf(acc[fm][fn][j] + bs, 0.0f) : 0.0f;
                    hout[(size_t)row * CPO + cg] = f2bf(v);
                }
        }
    }
}

// ---------------- final FC: out[g][c] = fcb[c] + dot(pooled[g,:], fcW[:,c]) ----------
// 8 graphs per block, thread = (4-graph group, column). fp32 exact.

__global__ __launch_bounds__(256)
void k_fc(const float* __restrict__ pooled, const float* __restrict__ fcW,
          const float* __restrict__ fcb, float* __restrict__ out) {
    __shared__ float sp[8][312];
    const int tid = threadIdx.x;
    const int g0 = blockIdx.x * 8;

    for (int k = tid; k < 8 * 312; k += 256)
        ((float*)sp)[k] = pooled[(size_t)g0 * 312 + k];
    __syncthreads();

    const int half = tid >> 7;       // 0..1 -> graphs g0+half*4 .. +3
    const int c = tid & 127;
    float b = fcb[c];
    float acc0 = b, acc1 = b, acc2 = b, acc3 = b;
    const float* wp = fcW + c;
    const float* p0 = sp[half * 4 + 0];
    const float* p1 = sp[half * 4 + 1];
    const float* p2 = sp[half * 4 + 2];
    const float* p3 = sp[half * 4 + 3];
    #pragma unroll 4
    for (int k = 0; k < 312; ++k) {
        float w = wp[(size_t)k * 128];
        acc0 = fmaf(p0[k], w, acc0);
        acc1 = fmaf(p1[k], w, acc1);
        acc2 = fmaf(p2[k], w, acc2);
        acc3 = fmaf(p3[k], w, acc3);
    }
    float* o = out + (size_t)(g0 + half * 4) * 128 + c;
    o[0] = acc0; o[128] = acc1; o[256] = acc2; o[384] = acc3;
}

// ---------------- launch ----------------

extern "C" void kernel_launch(void* const* d_in, const int* in_sizes, int n_in,
                              void* d_out, int out_size, void* d_ws, size_t ws_size,
                              hipStream_t stream) {
    const float* x    = (const float*)d_in[0];
    const int*   ei   = (const int*)d_in[1];
    const int*   srcv = ei;
    const int*   dstv = ei + NE;
    const int*   batch = (const int*)d_in[2];
    const float* W1 = (const float*)d_in[3];
    const float* b1 = (const float*)d_in[4];
    const float* W2 = (const float*)d_in[5];
    const float* b2 = (const float*)d_in[6];
    const float* W3 = (const float*)d_in[7];
    const float* b3 = (const float*)d_in[8];
    const float* fcW = (const float*)d_in[9];
    const float* fcb = (const float*)d_in[10];
    float* out = (float*)d_out;

    char* ws = (char*)d_ws;
    size_t off = 0;
    auto take = [&](size_t bytes) -> void* {
        void* p = ws + off;
        off += (bytes + 255) & ~(size_t)255;
        return p;
    };
    int*    counts   = (int*)take((size_t)NN * 4);
    int*    rowstart = (int*)take((size_t)(NN + 1) * 4);
    int*    cursor   = (int*)take((size_t)NN * 4);
    float*  dis      = (float*)take((size_t)NN * 4);
    int*    bsum     = (int*)take(512 * 4);
    int*    col      = (int*)take((size_t)NE * 4);
    float*  wgt      = (float*)take((size_t)NE * 4);
    ushort* R1       = (ushort*)take((size_t)NN * 160 * 2);  // xb / A2 / A3
    ushort* R2       = (ushort*)take((size_t)NN * 160 * 2);  // A1 / h2
    ushort* R3       = (ushort*)take((size_t)NN * 96 * 2);   // h1
    float*  pooled   = (float*)take((size_t)NG * 312 * 4);
    ushort* W1T      = (ushort*)take((size_t)78 * 96 * 2);
    ushort* W2T      = (ushort*)take((size_t)156 * 96 * 2);
    ushort* W3T      = (ushort*)take((size_t)312 * 160 * 2);

    ushort* xb = R1;   // [NN][96]
    ushort* A1 = R2;   // [NN][96]
    ushort* h1 = R3;   // [NN][96]
    ushort* A2 = R1;   // [NN][96]  (xb dead)
    ushort* h2 = R2;   // [NN][160] (A1 dead)
    ushort* A3 = R1;   // [NN][160] (A2 dead)

    hipMemsetAsync(counts, 0, (size_t)NN * 4, stream);
    hipMemsetAsync(cursor, 0, (size_t)NN * 4, stream);
    hipMemsetAsync(pooled, 0, (size_t)NG * 312 * 4, stream);

    k_count<<<NE / 256, 256, 0, stream>>>(dstv, counts);
    k_dis<<<NN / 256, 256, 0, stream>>>(counts, dis);
    k_scanA<<<NN / 256, 256, 0, stream>>>(counts, rowstart, bsum);
    k_scanB<<<1, 512, 0, stream>>>(bsum);
    k_scanC<<<NN / 256, 256, 0, stream>>>(rowstart, bsum);
    k_fill<<<NE / 256, 256, 0, stream>>>(srcv, dstv, rowstart, cursor, dis, col, wgt);

    k_prepW<78, 78, 96><<<(78 * 96 + 255) / 256, 256, 0, stream>>>(W1, W1T);
    k_prepW<78, 156, 96><<<(156 * 96 + 255) / 256, 256, 0, stream>>>(W2, W2T);
    k_prepW<156, 312, 160><<<(312 * 160 + 255) / 256, 256, 0, stream>>>(W3, W3T);
    k_prepX<<<NN * 96 / 256, 256, 0, stream>>>(x, xb);

    // layer 1
    k_agg8<96><<<NN * 12 / 256, 256, 0, stream>>>(xb, rowstart, col, wgt, dis, A1);
    k_mfma<96, 16, 78, 96, false><<<dim3(2, NN / 64), 256, 0, stream>>>(A1, W1T, b1, nullptr, h1, nullptr);
    // layer 2
    k_agg8<96><<<NN * 12 / 256, 256, 0, stream>>>(h1, rowstart, col, wgt, dis, A2);
    k_mfma<96, 16, 156, 160, false><<<dim3(3, NN / 64), 256, 0, stream>>>(A2, W2T, b2, nullptr, h2, nullptr);
    // layer 3 + pool
    k_agg8<160><<<NN * 20 / 256, 256, 0, stream>>>(h2, rowstart, col, wgt, dis, A3);
    k_mfma<160, 24, 312, 312, true><<<dim3(5, NN / 64), 256, 0, stream>>>(A3, W3T, b3, batch, nullptr, pooled);
    // FC (fp32, 8 graphs/block, 512 blocks)
    k_fc<<<NG / 8, 256, 0, stream>>>(pooled, fcW, fcb, out);
}

// Round 8
// 392.719 us; speedup vs baseline: 2.3673x; 1.0631x over previous
//
#include <hip/hip_runtime.h>

#define NN 131072   // nodes
#define NE 524288   // edges
#define NG 4096     // graphs

typedef __attribute__((ext_vector_type(8))) short bfx8;
typedef __attribute__((ext_vector_type(4))) float f32x4;

static __device__ __forceinline__ ushort f2bf(float f) {
    union { float f; unsigned u; } v; v.f = f;
    unsigned r = (v.u + 0x7fff + ((v.u >> 16) & 1)) >> 16;   // RNE
    return (ushort)r;
}
static __device__ __forceinline__ float bf2f(short s) {
    union { unsigned u; float f; } v;
    v.u = ((unsigned)(ushort)s) << 16;
    return v.f;
}

// ---------------- preprocessing: degree, dis, CSR ----------------

__global__ void k_count(const int* __restrict__ dst, int* __restrict__ counts) {
    int e = blockIdx.x * blockDim.x + threadIdx.x;
    if (e < NE) atomicAdd(&counts[dst[e]], 1);
}

__global__ void k_dis(const int* __restrict__ counts, float* __restrict__ dis) {
    int i = blockIdx.x * blockDim.x + threadIdx.x;
    if (i < NN) dis[i] = rsqrtf((float)(counts[i] + 1));  // +1 self-loop
}

__global__ void k_scanA(const int* __restrict__ in, int* __restrict__ out, int* __restrict__ bsum) {
    __shared__ int s[256];
    int t = threadIdx.x;
    int i = blockIdx.x * 256 + t;
    int v = in[i];
    s[t] = v;
    __syncthreads();
    for (int off = 1; off < 256; off <<= 1) {
        int x = (t >= off) ? s[t - off] : 0;
        __syncthreads();
        s[t] += x;
        __syncthreads();
    }
    out[i] = s[t] - v;
    if (t == 255) bsum[blockIdx.x] = s[t];
}

__global__ void k_scanB(int* __restrict__ bsum) {
    __shared__ int s[512];
    int t = threadIdx.x;
    int v = bsum[t];
    s[t] = v;
    __syncthreads();
    for (int off = 1; off < 512; off <<= 1) {
        int x = (t >= off) ? s[t - off] : 0;
        __syncthreads();
        s[t] += x;
        __syncthreads();
    }
    bsum[t] = s[t] - v;
}

__global__ void k_scanC(int* __restrict__ rowstart, const int* __restrict__ bsum) {
    int t = threadIdx.x;
    int i = blockIdx.x * 256 + t;
    rowstart[i] += bsum[blockIdx.x];
    if (i == 0) rowstart[NN] = NE;
}

__global__ void k_fill(const int* __restrict__ src, const int* __restrict__ dst,
                       const int* __restrict__ rowstart, int* __restrict__ cursor,
                       const float* __restrict__ dis,
                       int* __restrict__ col, float* __restrict__ wgt) {
    int e = blockIdx.x * blockDim.x + threadIdx.x;
    if (e >= NE) return;
    int s = src[e], d = dst[e];
    int pos = rowstart[d] + atomicAdd(&cursor[d], 1);
    col[pos] = s;
    wgt[pos] = dis[s] * dis[d];
}

// W [CI][CO] fp32 -> WT [CO][KP] bf16 (transposed, zero-padded K)
template<int CI, int CO, int KP>
__global__ void k_prepW(const float* __restrict__ W, ushort* __restrict__ WT) {
    int idx = blockIdx.x * 256 + threadIdx.x;
    if (idx >= CO * KP) return;
    int n = idx / KP, k = idx - n * KP;
    float v = (k < CI) ? W[k * CO + n] : 0.0f;
    WT[idx] = f2bf(v);
}

// x [NN][78] fp32 -> xb [NN][96] bf16 zero-padded
__global__ void k_prepX(const float* __restrict__ x, ushort* __restrict__ xb) {
    int idx = blockIdx.x * 256 + threadIdx.x;   // exact NN*96
    int i = idx / 96, c = idx - i * 96;
    xb[idx] = (c < 78) ? f2bf(x[i * 78 + c]) : (ushort)0;
}

// ---------------- aggregation (bf16 in/out, fp32 accum) ----------------

template<int CP>
__global__ __launch_bounds__(256)
void k_agg8(const ushort* __restrict__ hin, const int* __restrict__ rowstart,
            const int* __restrict__ col, const float* __restrict__ wgt,
            const float* __restrict__ dis, ushort* __restrict__ out) {
    constexpr int CH = CP / 8;
    int idx = blockIdx.x * 256 + threadIdx.x;   // exact NN*CH threads
    int i = idx / CH;
    int ch = (idx - i * CH) * 8;
    const ushort* base = hin + ch;

    float d = dis[i];
    bfx8 self = *(const bfx8*)(hin + (size_t)i * CP + ch);
    float acc[8];
    #pragma unroll
    for (int k = 0; k < 8; ++k) acc[k] = d * d * bf2f(self[k]);

    int j = rowstart[i], j1 = rowstart[i + 1];
    for (; j + 4 <= j1; j += 4) {
        int c0 = col[j], c1 = col[j + 1], c2 = col[j + 2], c3 = col[j + 3];
        float w0 = wgt[j], w1 = wgt[j + 1], w2 = wgt[j + 2], w3 = wgt[j + 3];
        bfx8 g0 = *(const bfx8*)(base + (size_t)c0 * CP);
        bfx8 g1 = *(const bfx8*)(base + (size_t)c1 * CP);
        bfx8 g2 = *(const bfx8*)(base + (size_t)c2 * CP);
        bfx8 g3 = *(const bfx8*)(base + (size_t)c3 * CP);
        #pragma unroll
        for (int k = 0; k < 8; ++k) {
            acc[k] = fmaf(w0, bf2f(g0[k]), acc[k]);
            acc[k] = fmaf(w1, bf2f(g1[k]), acc[k]);
            acc[k] = fmaf(w2, bf2f(g2[k]), acc[k]);
            acc[k] = fmaf(w3, bf2f(g3[k]), acc[k]);
        }
    }
    for (; j < j1; ++j) {
        int c = col[j];
        float w = wgt[j];
        bfx8 g = *(const bfx8*)(base + (size_t)c * CP);
        #pragma unroll
        for (int k = 0; k < 8; ++k) acc[k] = fmaf(w, bf2f(g[k]), acc[k]);
    }

    bfx8 ov;
    #pragma unroll
    for (int k = 0; k < 8; ++k) ov[k] = (short)f2bf(acc[k]);
    *(bfx8*)(out + (size_t)i * CP + ch) = ov;
}

// ---------------- bf16 MFMA GEMM, panel-loop: A staged ONCE, B per panel from L2 ----
// A [NN][KP] bf16, BT [CO][KP] bf16. Block = 64-row tile; loop over all 64-col panels.
// LDS XOR-swizzle (T2): chunk pos = (c&~7)|((c&7)^(row&7)), write AND read side.

template<int KP, int LCH, int CO, int CPO, bool POOL>
__global__ __launch_bounds__(256)
void k_mfma(const ushort* __restrict__ A, const ushort* __restrict__ BT,
            const float* __restrict__ bias, const int* __restrict__ batch,
            ushort* __restrict__ hout, float* __restrict__ pooled) {
    constexpr int NCH = KP / 8;           // data chunks per row
    constexpr int LP  = LCH * 8;          // LDS row pitch in bf16 elems
    constexpr int NP  = (CO + 63) / 64;   // number of 64-col panels
    __shared__ ushort sA[64 * LP];
    __shared__ ushort sB[64 * LP];

    const int tid  = threadIdx.x;
    const int row0 = blockIdx.x * 64;

    // stage A-tile once (HBM)
    for (int id = tid; id < 64 * NCH; id += 256) {
        int r = id / NCH, kc = id - r * NCH;
        int swz = (kc & ~7) | ((kc & 7) ^ (r & 7));
        ((int4*)(sA + r * LP))[swz] = ((const int4*)(A + (size_t)(row0 + r) * KP))[kc];
    }

    auto stageB = [&](int p) {
        int cbase = p * 64;
        for (int id = tid; id < 64 * NCH; id += 256) {
            int r = id / NCH, kc = id - r * NCH;
            int swz = (kc & ~7) | ((kc & 7) ^ (r & 7));
            int4 vb = {0, 0, 0, 0};
            int bc = cbase + r;
            if (bc < CO) vb = ((const int4*)(BT + (size_t)bc * KP))[kc];
            ((int4*)(sB + r * LP))[swz] = vb;
        }
    };

    stageB(0);
    __syncthreads();

    const int lane = tid & 63;
    const int wave = tid >> 6;
    const int wr = wave >> 1, wc = wave & 1;
    const int l15 = lane & 15, l4 = lane >> 4;
    const int r7 = l15 & 7;
    const int rowA0 = wr * 32 + l15;
    const int rowB0 = wc * 32 + l15;
    const int gbase = row0 + wr * 32;

    #pragma unroll
    for (int p = 0; p < NP; ++p) {
        f32x4 acc[2][2] = {};
        #pragma unroll
        for (int ks = 0; ks < KP / 32; ++ks) {
            int chunk = l4 + ks * 4;
            int swz = (chunk & ~7) | ((chunk & 7) ^ r7);
            int off = swz * 8;
            bfx8 a0 = *(const bfx8*)(sA + rowA0 * LP + off);
            bfx8 a1 = *(const bfx8*)(sA + (rowA0 + 16) * LP + off);
            bfx8 b0 = *(const bfx8*)(sB + rowB0 * LP + off);
            bfx8 b1 = *(const bfx8*)(sB + (rowB0 + 16) * LP + off);
            acc[0][0] = __builtin_amdgcn_mfma_f32_16x16x32_bf16(a0, b0, acc[0][0], 0, 0, 0);
            acc[0][1] = __builtin_amdgcn_mfma_f32_16x16x32_bf16(a0, b1, acc[0][1], 0, 0, 0);
            acc[1][0] = __builtin_amdgcn_mfma_f32_16x16x32_bf16(a1, b0, acc[1][0], 0, 0, 0);
            acc[1][1] = __builtin_amdgcn_mfma_f32_16x16x32_bf16(a1, b1, acc[1][1], 0, 0, 0);
        }

        // epilogue for this panel. D-frag: row = fm*16 + (l>>4)*4 + j, col = fn*16 + (l&15).
        if constexpr (POOL) {
            const bool uni = (batch[gbase] == batch[gbase + 31]);
            #pragma unroll
            for (int fn = 0; fn < 2; ++fn) {
                int cg = p * 64 + wc * 32 + fn * 16 + l15;
                bool cok = cg < CO;
                float bs = cok ? bias[cg] : 0.0f;
                if (uni) {
                    float m = -1e30f;
                    #pragma unroll
                    for (int fm = 0; fm < 2; ++fm)
                        #pragma unroll
                        for (int j = 0; j < 4; ++j)
                            m = fmaxf(m, acc[fm][fn][j]);
                    m = fmaxf(m, __shfl_xor(m, 16));
                    m = fmaxf(m, __shfl_xor(m, 32));
                    if (l4 == 0 && cok) {
                        int g = batch[gbase];
                        float v = fmaxf(m + bs, 0.0f);
                        atomicMax((int*)&pooled[g * CO + cg], __float_as_int(v));
                    }
                } else {
                    #pragma unroll
                    for (int fm = 0; fm < 2; ++fm)
                        #pragma unroll
                        for (int j = 0; j < 4; ++j) {
                            if (cok) {
                                int rg = gbase + fm * 16 + l4 * 4 + j;
                                int g = batch[rg];
                                float v = fmaxf(acc[fm][fn][j] + bs, 0.0f);
                                atomicMax((int*)&pooled[g * CO + cg], __float_as_int(v));
                            }
                        }
                }
            }
        } else {
            #pragma unroll
            for (int fn = 0; fn < 2; ++fn) {
                int cg = p * 64 + wc * 32 + fn * 16 + l15;
                if (cg >= CPO) continue;
                float bs = (cg < CO) ? bias[cg] : 0.0f;
                #pragma unroll
                for (int fm = 0; fm < 2; ++fm)
                    #pragma unroll
                    for (int j = 0; j < 4; ++j) {
                        int row = gbase + fm * 16 + l4 * 4 + j;
                        float v = (cg < CO) ? fmaxf(acc[fm][fn][j] + bs, 0.0f) : 0.0f;
                        hout[(size_t)row * CPO + cg] = f2bf(v);
                    }
            }
        }

        if (p + 1 < NP) {
            __syncthreads();       // all waves done reading sB panel p
            stageB(p + 1);
            __syncthreads();       // panel p+1 ready
        }
    }
}

// ---------------- final FC: out[g][c] = fcb[c] + dot(pooled[g,:], fcW[:,c]) ----------

__global__ __launch_bounds__(256)
void k_fc(const float* __restrict__ pooled, const float* __restrict__ fcW,
          const float* __restrict__ fcb, float* __restrict__ out) {
    __shared__ float sp[8][312];
    const int tid = threadIdx.x;
    const int g0 = blockIdx.x * 8;

    for (int k = tid; k < 8 * 312; k += 256)
        ((float*)sp)[k] = pooled[(size_t)g0 * 312 + k];
    __syncthreads();

    const int half = tid >> 7;       // 0..1 -> graphs g0+half*4 .. +3
    const int c = tid & 127;
    float b = fcb[c];
    float acc0 = b, acc1 = b, acc2 = b, acc3 = b;
    const float* wp = fcW + c;
    const float* p0 = sp[half * 4 + 0];
    const float* p1 = sp[half * 4 + 1];
    const float* p2 = sp[half * 4 + 2];
    const float* p3 = sp[half * 4 + 3];
    #pragma unroll 4
    for (int k = 0; k < 312; ++k) {
        float w = wp[(size_t)k * 128];
        acc0 = fmaf(p0[k], w, acc0);
        acc1 = fmaf(p1[k], w, acc1);
        acc2 = fmaf(p2[k], w, acc2);
        acc3 = fmaf(p3[k], w, acc3);
    }
    float* o = out + (size_t)(g0 + half * 4) * 128 + c;
    o[0] = acc0; o[128] = acc1; o[256] = acc2; o[384] = acc3;
}

// ---------------- launch ----------------

extern "C" void kernel_launch(void* const* d_in, const int* in_sizes, int n_in,
                              void* d_out, int out_size, void* d_ws, size_t ws_size,
                              hipStream_t stream) {
    const float* x    = (const float*)d_in[0];
    const int*   ei   = (const int*)d_in[1];
    const int*   srcv = ei;
    const int*   dstv = ei + NE;
    const int*   batch = (const int*)d_in[2];
    const float* W1 = (const float*)d_in[3];
    const float* b1 = (const float*)d_in[4];
    const float* W2 = (const float*)d_in[5];
    const float* b2 = (const float*)d_in[6];
    const float* W3 = (const float*)d_in[7];
    const float* b3 = (const float*)d_in[8];
    const float* fcW = (const float*)d_in[9];
    const float* fcb = (const float*)d_in[10];
    float* out = (float*)d_out;

    char* ws = (char*)d_ws;
    size_t off = 0;
    auto take = [&](size_t bytes) -> void* {
        void* p = ws + off;
        off += (bytes + 255) & ~(size_t)255;
        return p;
    };
    int*    counts   = (int*)take((size_t)NN * 4);
    int*    rowstart = (int*)take((size_t)(NN + 1) * 4);
    int*    cursor   = (int*)take((size_t)NN * 4);
    float*  dis      = (float*)take((size_t)NN * 4);
    int*    bsum     = (int*)take(512 * 4);
    int*    col      = (int*)take((size_t)NE * 4);
    float*  wgt      = (float*)take((size_t)NE * 4);
    ushort* R1       = (ushort*)take((size_t)NN * 160 * 2);  // xb / A2 / A3
    ushort* R2       = (ushort*)take((size_t)NN * 160 * 2);  // A1 / h2
    ushort* R3       = (ushort*)take((size_t)NN * 96 * 2);   // h1
    float*  pooled   = (float*)take((size_t)NG * 312 * 4);
    ushort* W1T      = (ushort*)take((size_t)78 * 96 * 2);
    ushort* W2T      = (ushort*)take((size_t)156 * 96 * 2);
    ushort* W3T      = (ushort*)take((size_t)312 * 160 * 2);

    ushort* xb = R1;   // [NN][96]
    ushort* A1 = R2;   // [NN][96]
    ushort* h1 = R3;   // [NN][96]
    ushort* A2 = R1;   // [NN][96]  (xb dead)
    ushort* h2 = R2;   // [NN][160] (A1 dead)
    ushort* A3 = R1;   // [NN][160] (A2 dead)

    hipMemsetAsync(counts, 0, (size_t)NN * 4, stream);
    hipMemsetAsync(cursor, 0, (size_t)NN * 4, stream);
    hipMemsetAsync(pooled, 0, (size_t)NG * 312 * 4, stream);

    k_count<<<NE / 256, 256, 0, stream>>>(dstv, counts);
    k_dis<<<NN / 256, 256, 0, stream>>>(counts, dis);
    k_scanA<<<NN / 256, 256, 0, stream>>>(counts, rowstart, bsum);
    k_scanB<<<1, 512, 0, stream>>>(bsum);
    k_scanC<<<NN / 256, 256, 0, stream>>>(rowstart, bsum);
    k_fill<<<NE / 256, 256, 0, stream>>>(srcv, dstv, rowstart, cursor, dis, col, wgt);

    k_prepW<78, 78, 96><<<(78 * 96 + 255) / 256, 256, 0, stream>>>(W1, W1T);
    k_prepW<78, 156, 96><<<(156 * 96 + 255) / 256, 256, 0, stream>>>(W2, W2T);
    k_prepW<156, 312, 160><<<(312 * 160 + 255) / 256, 256, 0, stream>>>(W3, W3T);
    k_prepX<<<NN * 96 / 256, 256, 0, stream>>>(x, xb);

    // layer 1
    k_agg8<96><<<NN * 12 / 256, 256, 0, stream>>>(xb, rowstart, col, wgt, dis, A1);
    k_mfma<96, 16, 78, 96, false><<<NN / 64, 256, 0, stream>>>(A1, W1T, b1, nullptr, h1, nullptr);
    // layer 2
    k_agg8<96><<<NN * 12 / 256, 256, 0, stream>>>(h1, rowstart, col, wgt, dis, A2);
    k_mfma<96, 16, 156, 160, false><<<NN / 64, 256, 0, stream>>>(A2, W2T, b2, nullptr, h2, nullptr);
    // layer 3 + pool
    k_agg8<160><<<NN * 20 / 256, 256, 0, stream>>>(h2, rowstart, col, wgt, dis, A3);
    k_mfma<160, 24, 312, 312, true><<<NN / 64, 256, 0, stream>>>(A3, W3T, b3, batch, nullptr, pooled);
    // FC (fp32, 8 graphs/block, 512 blocks)
    k_fc<<<NG / 8, 256, 0, stream>>>(pooled, fcW, fcb, out);
}

// Round 9
// 380.971 us; speedup vs baseline: 2.4403x; 1.0308x over previous
//
#include <hip/hip_runtime.h>

#define NN 131072   // nodes
#define NE 524288   // edges
#define NG 4096     // graphs

typedef __attribute__((ext_vector_type(8))) short bfx8;
typedef __attribute__((ext_vector_type(4))) float f32x4;

static __device__ __forceinline__ ushort f2bf(float f) {
    union { float f; unsigned u; } v; v.f = f;
    unsigned r = (v.u + 0x7fff + ((v.u >> 16) & 1)) >> 16;   // RNE
    return (ushort)r;
}
static __device__ __forceinline__ float bf2f(short s) {
    union { unsigned u; float f; } v;
    v.u = ((unsigned)(ushort)s) << 16;
    return v.f;
}

// ---------------- preprocessing: degree, dis, CSR ----------------

__global__ void k_count(const int* __restrict__ dst, int* __restrict__ counts) {
    int e = blockIdx.x * blockDim.x + threadIdx.x;
    if (e < NE) atomicAdd(&counts[dst[e]], 1);
}

__global__ void k_dis(const int* __restrict__ counts, float* __restrict__ dis) {
    int i = blockIdx.x * blockDim.x + threadIdx.x;
    if (i < NN) dis[i] = rsqrtf((float)(counts[i] + 1));  // +1 self-loop
}

__global__ void k_scanA(const int* __restrict__ in, int* __restrict__ out, int* __restrict__ bsum) {
    __shared__ int s[256];
    int t = threadIdx.x;
    int i = blockIdx.x * 256 + t;
    int v = in[i];
    s[t] = v;
    __syncthreads();
    for (int off = 1; off < 256; off <<= 1) {
        int x = (t >= off) ? s[t - off] : 0;
        __syncthreads();
        s[t] += x;
        __syncthreads();
    }
    out[i] = s[t] - v;
    if (t == 255) bsum[blockIdx.x] = s[t];
}

__global__ void k_scanB(int* __restrict__ bsum) {
    __shared__ int s[512];
    int t = threadIdx.x;
    int v = bsum[t];
    s[t] = v;
    __syncthreads();
    for (int off = 1; off < 512; off <<= 1) {
        int x = (t >= off) ? s[t - off] : 0;
        __syncthreads();
        s[t] += x;
        __syncthreads();
    }
    bsum[t] = s[t] - v;
}

__global__ void k_scanC(int* __restrict__ rowstart, const int* __restrict__ bsum) {
    int t = threadIdx.x;
    int i = blockIdx.x * 256 + t;
    rowstart[i] += bsum[blockIdx.x];
    if (i == 0) rowstart[NN] = NE;
}

__global__ void k_fill(const int* __restrict__ src, const int* __restrict__ dst,
                       const int* __restrict__ rowstart, int* __restrict__ cursor,
                       const float* __restrict__ dis,
                       int* __restrict__ col, float* __restrict__ wgt) {
    int e = blockIdx.x * blockDim.x + threadIdx.x;
    if (e >= NE) return;
    int s = src[e], d = dst[e];
    int pos = rowstart[d] + atomicAdd(&cursor[d], 1);
    col[pos] = s;
    wgt[pos] = dis[s] * dis[d];
}

// W [CI][CO] fp32 -> WT [CO][KP] bf16 (transposed, zero-padded K)
template<int CI, int CO, int KP>
__global__ void k_prepW(const float* __restrict__ W, ushort* __restrict__ WT) {
    int idx = blockIdx.x * 256 + threadIdx.x;
    if (idx >= CO * KP) return;
    int n = idx / KP, k = idx - n * KP;
    float v = (k < CI) ? W[k * CO + n] : 0.0f;
    WT[idx] = f2bf(v);
}

// x [NN][78] fp32 -> xb [NN][96] bf16 zero-padded
__global__ void k_prepX(const float* __restrict__ x, ushort* __restrict__ xb) {
    int idx = blockIdx.x * 256 + threadIdx.x;   // exact NN*96
    int i = idx / 96, c = idx - i * 96;
    xb[idx] = (c < 78) ? f2bf(x[i * 78 + c]) : (ushort)0;
}

// ---------------- aggregation (bf16 in/out, fp32 accum) ----------------

template<int CP>
__global__ __launch_bounds__(256)
void k_agg8(const ushort* __restrict__ hin, const int* __restrict__ rowstart,
            const int* __restrict__ col, const float* __restrict__ wgt,
            const float* __restrict__ dis, ushort* __restrict__ out) {
    constexpr int CH = CP / 8;
    int idx = blockIdx.x * 256 + threadIdx.x;   // exact NN*CH threads
    int i = idx / CH;
    int ch = (idx - i * CH) * 8;
    const ushort* base = hin + ch;

    float d = dis[i];
    bfx8 self = *(const bfx8*)(hin + (size_t)i * CP + ch);
    float acc[8];
    #pragma unroll
    for (int k = 0; k < 8; ++k) acc[k] = d * d * bf2f(self[k]);

    int j = rowstart[i], j1 = rowstart[i + 1];
    for (; j + 4 <= j1; j += 4) {
        int c0 = col[j], c1 = col[j + 1], c2 = col[j + 2], c3 = col[j + 3];
        float w0 = wgt[j], w1 = wgt[j + 1], w2 = wgt[j + 2], w3 = wgt[j + 3];
        bfx8 g0 = *(const bfx8*)(base + (size_t)c0 * CP);
        bfx8 g1 = *(const bfx8*)(base + (size_t)c1 * CP);
        bfx8 g2 = *(const bfx8*)(base + (size_t)c2 * CP);
        bfx8 g3 = *(const bfx8*)(base + (size_t)c3 * CP);
        #pragma unroll
        for (int k = 0; k < 8; ++k) {
            acc[k] = fmaf(w0, bf2f(g0[k]), acc[k]);
            acc[k] = fmaf(w1, bf2f(g1[k]), acc[k]);
            acc[k] = fmaf(w2, bf2f(g2[k]), acc[k]);
            acc[k] = fmaf(w3, bf2f(g3[k]), acc[k]);
        }
    }
    for (; j < j1; ++j) {
        int c = col[j];
        float w = wgt[j];
        bfx8 g = *(const bfx8*)(base + (size_t)c * CP);
        #pragma unroll
        for (int k = 0; k < 8; ++k) acc[k] = fmaf(w, bf2f(g[k]), acc[k]);
    }

    bfx8 ov;
    #pragma unroll
    for (int k = 0; k < 8; ++k) ov[k] = (short)f2bf(acc[k]);
    *(bfx8*)(out + (size_t)i * CP + ch) = ov;
}

// ---------------- bf16 MFMA GEMM: A staged once in LDS, B direct from L2 ----------
// A [NN][KP] bf16, BT [CO][KP] bf16 (tiny, L2-resident). Block = 64-row tile,
// 4 waves (2x2 of 32x32), loop over 64-col panels. No in-loop barriers.
// A LDS XOR-swizzle (T2): chunk pos = (c&~7)|((c&7)^(row&7)), write AND read.

template<int KP, int LCH, int CO, int CPO, bool POOL>
__global__ __launch_bounds__(256)
void k_mfma(const ushort* __restrict__ A, const ushort* __restrict__ BT,
            const float* __restrict__ bias, const int* __restrict__ batch,
            ushort* __restrict__ hout, float* __restrict__ pooled) {
    constexpr int NCH = KP / 8;           // data chunks per row
    constexpr int LP  = LCH * 8;          // LDS row pitch in bf16 elems
    constexpr int NP  = (CO + 63) / 64;   // number of 64-col panels
    __shared__ ushort sA[64 * LP];

    const int tid  = threadIdx.x;
    const int row0 = blockIdx.x * 64;

    // stage A-tile once
    for (int id = tid; id < 64 * NCH; id += 256) {
        int r = id / NCH, kc = id - r * NCH;
        int swz = (kc & ~7) | ((kc & 7) ^ (r & 7));
        ((int4*)(sA + r * LP))[swz] = ((const int4*)(A + (size_t)(row0 + r) * KP))[kc];
    }
    __syncthreads();

    const int lane = tid & 63;
    const int wave = tid >> 6;
    const int wr = wave >> 1, wc = wave & 1;
    const int l15 = lane & 15, l4 = lane >> 4;
    const int r7 = l15 & 7;
    const int rowA0 = wr * 32 + l15;
    const int gbase = row0 + wr * 32;
    const int koff = l4 * 8;

    #pragma unroll
    for (int p = 0; p < NP; ++p) {
        const int bc0 = p * 64 + wc * 32 + l15;       // B row for b0
        f32x4 acc[2][2] = {};
        #pragma unroll
        for (int ks = 0; ks < KP / 32; ++ks) {
            int chunk = l4 + ks * 4;
            int swz = (chunk & ~7) | ((chunk & 7) ^ r7);
            int off = swz * 8;
            bfx8 a0 = *(const bfx8*)(sA + rowA0 * LP + off);
            bfx8 a1 = *(const bfx8*)(sA + (rowA0 + 16) * LP + off);
            bfx8 b0 = {0,0,0,0,0,0,0,0}, b1 = {0,0,0,0,0,0,0,0};
            if (bc0 < CO)      b0 = *(const bfx8*)(BT + (size_t)bc0 * KP + koff + ks * 32);
            if (bc0 + 16 < CO) b1 = *(const bfx8*)(BT + (size_t)(bc0 + 16) * KP + koff + ks * 32);
            acc[0][0] = __builtin_amdgcn_mfma_f32_16x16x32_bf16(a0, b0, acc[0][0], 0, 0, 0);
            acc[0][1] = __builtin_amdgcn_mfma_f32_16x16x32_bf16(a0, b1, acc[0][1], 0, 0, 0);
            acc[1][0] = __builtin_amdgcn_mfma_f32_16x16x32_bf16(a1, b0, acc[1][0], 0, 0, 0);
            acc[1][1] = __builtin_amdgcn_mfma_f32_16x16x32_bf16(a1, b1, acc[1][1], 0, 0, 0);
        }

        // epilogue. D-frag: row = fm*16 + (l>>4)*4 + j, col = fn*16 + (l&15).
        if constexpr (POOL) {
            const bool uni = (batch[gbase] == batch[gbase + 31]);
            #pragma unroll
            for (int fn = 0; fn < 2; ++fn) {
                int cg = p * 64 + wc * 32 + fn * 16 + l15;
                bool cok = cg < CO;
                float bs = cok ? bias[cg] : 0.0f;
                if (uni) {
                    float m = -1e30f;
                    #pragma unroll
                    for (int fm = 0; fm < 2; ++fm)
                        #pragma unroll
                        for (int j = 0; j < 4; ++j)
                            m = fmaxf(m, acc[fm][fn][j]);
                    m = fmaxf(m, __shfl_xor(m, 16));
                    m = fmaxf(m, __shfl_xor(m, 32));
                    if (l4 == 0 && cok) {
                        int g = batch[gbase];
                        float v = fmaxf(m + bs, 0.0f);
                        atomicMax((int*)&pooled[g * CO + cg], __float_as_int(v));
                    }
                } else {
                    #pragma unroll
                    for (int fm = 0; fm < 2; ++fm)
                        #pragma unroll
                        for (int j = 0; j < 4; ++j) {
                            if (cok) {
                                int rg = gbase + fm * 16 + l4 * 4 + j;
                                int g = batch[rg];
                                float v = fmaxf(acc[fm][fn][j] + bs, 0.0f);
                                atomicMax((int*)&pooled[g * CO + cg], __float_as_int(v));
                            }
                        }
                }
            }
        } else {
            #pragma unroll
            for (int fn = 0; fn < 2; ++fn) {
                int cg = p * 64 + wc * 32 + fn * 16 + l15;
                if (cg >= CPO) continue;
                float bs = (cg < CO) ? bias[cg] : 0.0f;
                #pragma unroll
                for (int fm = 0; fm < 2; ++fm)
                    #pragma unroll
                    for (int j = 0; j < 4; ++j) {
                        int row = gbase + fm * 16 + l4 * 4 + j;
                        float v = (cg < CO) ? fmaxf(acc[fm][fn][j] + bs, 0.0f) : 0.0f;
                        hout[(size_t)row * CPO + cg] = f2bf(v);
                    }
            }
        }
    }
}

// ---------------- final FC: out[g][c] = fcb[c] + dot(pooled[g,:], fcW[:,c]) ----------

__global__ __launch_bounds__(256)
void k_fc(const float* __restrict__ pooled, const float* __restrict__ fcW,
          const float* __restrict__ fcb, float* __restrict__ out) {
    __shared__ float sp[8][312];
    const int tid = threadIdx.x;
    const int g0 = blockIdx.x * 8;

    for (int k = tid; k < 8 * 312; k += 256)
        ((float*)sp)[k] = pooled[(size_t)g0 * 312 + k];
    __syncthreads();

    const int half = tid >> 7;       // 0..1 -> graphs g0+half*4 .. +3
    const int c = tid & 127;
    float b = fcb[c];
    float acc0 = b, acc1 = b, acc2 = b, acc3 = b;
    const float* wp = fcW + c;
    const float* p0 = sp[half * 4 + 0];
    const float* p1 = sp[half * 4 + 1];
    const float* p2 = sp[half * 4 + 2];
    const float* p3 = sp[half * 4 + 3];
    #pragma unroll 4
    for (int k = 0; k < 312; ++k) {
        float w = wp[(size_t)k * 128];
        acc0 = fmaf(p0[k], w, acc0);
        acc1 = fmaf(p1[k], w, acc1);
        acc2 = fmaf(p2[k], w, acc2);
        acc3 = fmaf(p3[k], w, acc3);
    }
    float* o = out + (size_t)(g0 + half * 4) * 128 + c;
    o[0] = acc0; o[128] = acc1; o[256] = acc2; o[384] = acc3;
}

// ---------------- launch ----------------

extern "C" void kernel_launch(void* const* d_in, const int* in_sizes, int n_in,
                              void* d_out, int out_size, void* d_ws, size_t ws_size,
                              hipStream_t stream) {
    const float* x    = (const float*)d_in[0];
    const int*   ei   = (const int*)d_in[1];
    const int*   srcv = ei;
    const int*   dstv = ei + NE;
    const int*   batch = (const int*)d_in[2];
    const float* W1 = (const float*)d_in[3];
    const float* b1 = (const float*)d_in[4];
    const float* W2 = (const float*)d_in[5];
    const float* b2 = (const float*)d_in[6];
    const float* W3 = (const float*)d_in[7];
    const float* b3 = (const float*)d_in[8];
    const float* fcW = (const float*)d_in[9];
    const float* fcb = (const float*)d_in[10];
    float* out = (float*)d_out;

    char* ws = (char*)d_ws;
    size_t off = 0;
    auto take = [&](size_t bytes) -> void* {
        void* p = ws + off;
        off += (bytes + 255) & ~(size_t)255;
        return p;
    };
    int*    counts   = (int*)take((size_t)NN * 4);
    int*    rowstart = (int*)take((size_t)(NN + 1) * 4);
    int*    cursor   = (int*)take((size_t)NN * 4);
    float*  dis      = (float*)take((size_t)NN * 4);
    int*    bsum     = (int*)take(512 * 4);
    int*    col      = (int*)take((size_t)NE * 4);
    float*  wgt      = (float*)take((size_t)NE * 4);
    ushort* R1       = (ushort*)take((size_t)NN * 160 * 2);  // xb / A2 / A3
    ushort* R2       = (ushort*)take((size_t)NN * 160 * 2);  // A1 / h2
    ushort* R3       = (ushort*)take((size_t)NN * 96 * 2);   // h1
    float*  pooled   = (float*)take((size_t)NG * 312 * 4);
    ushort* W1T      = (ushort*)take((size_t)78 * 96 * 2);
    ushort* W2T      = (ushort*)take((size_t)156 * 96 * 2);
    ushort* W3T      = (ushort*)take((size_t)312 * 160 * 2);

    ushort* xb = R1;   // [NN][96]
    ushort* A1 = R2;   // [NN][96]
    ushort* h1 = R3;   // [NN][96]
    ushort* A2 = R1;   // [NN][96]  (xb dead)
    ushort* h2 = R2;   // [NN][160] (A1 dead)
    ushort* A3 = R1;   // [NN][160] (A2 dead)

    hipMemsetAsync(counts, 0, (size_t)NN * 4, stream);
    hipMemsetAsync(cursor, 0, (size_t)NN * 4, stream);
    hipMemsetAsync(pooled, 0, (size_t)NG * 312 * 4, stream);

    k_count<<<NE / 256, 256, 0, stream>>>(dstv, counts);
    k_dis<<<NN / 256, 256, 0, stream>>>(counts, dis);
    k_scanA<<<NN / 256, 256, 0, stream>>>(counts, rowstart, bsum);
    k_scanB<<<1, 512, 0, stream>>>(bsum);
    k_scanC<<<NN / 256, 256, 0, stream>>>(rowstart, bsum);
    k_fill<<<NE / 256, 256, 0, stream>>>(srcv, dstv, rowstart, cursor, dis, col, wgt);

    k_prepW<78, 78, 96><<<(78 * 96 + 255) / 256, 256, 0, stream>>>(W1, W1T);
    k_prepW<78, 156, 96><<<(156 * 96 + 255) / 256, 256, 0, stream>>>(W2, W2T);
    k_prepW<156, 312, 160><<<(312 * 160 + 255) / 256, 256, 0, stream>>>(W3, W3T);
    k_prepX<<<NN * 96 / 256, 256, 0, stream>>>(x, xb);

    // layer 1
    k_agg8<96><<<NN * 12 / 256, 256, 0, stream>>>(xb, rowstart, col, wgt, dis, A1);
    k_mfma<96, 16, 78, 96, false><<<NN / 64, 256, 0, stream>>>(A1, W1T, b1, nullptr, h1, nullptr);
    // layer 2
    k_agg8<96><<<NN * 12 / 256, 256, 0, stream>>>(h1, rowstart, col, wgt, dis, A2);
    k_mfma<96, 16, 156, 160, false><<<NN / 64, 256, 0, stream>>>(A2, W2T, b2, nullptr, h2, nullptr);
    // layer 3 + pool
    k_agg8<160><<<NN * 20 / 256, 256, 0, stream>>>(h2, rowstart, col, wgt, dis, A3);
    k_mfma<160, 24, 312, 312, true><<<NN / 64, 256, 0, stream>>>(A3, W3T, b3, batch, nullptr, pooled);
    // FC (fp32, 8 graphs/block, 512 blocks)
    k_fc<<<NG / 8, 256, 0, stream>>>(pooled, fcW, fcb, out);
}

// Round 10
// 356.918 us; speedup vs baseline: 2.6047x; 1.0674x over previous
//
#include <hip/hip_runtime.h>

#define NN 131072   // nodes
#define NE 524288   // edges
#define NG 4096     // graphs

typedef __attribute__((ext_vector_type(8))) short bfx8;
typedef __attribute__((ext_vector_type(4))) float f32x4;

static __device__ __forceinline__ ushort f2bf(float f) {
    union { float f; unsigned u; } v; v.f = f;
    unsigned r = (v.u + 0x7fff + ((v.u >> 16) & 1)) >> 16;   // RNE
    return (ushort)r;
}
static __device__ __forceinline__ float bf2f(short s) {
    union { unsigned u; float f; } v;
    v.u = ((unsigned)(ushort)s) << 16;
    return v.f;
}

// ---------------- preprocessing: degree, dis, CSR ----------------

__global__ void k_count(const int* __restrict__ dst, int* __restrict__ counts) {
    int e = blockIdx.x * blockDim.x + threadIdx.x;
    if (e < NE) atomicAdd(&counts[dst[e]], 1);
}

__global__ void k_dis(const int* __restrict__ counts, float* __restrict__ dis) {
    int i = blockIdx.x * blockDim.x + threadIdx.x;
    if (i < NN) dis[i] = rsqrtf((float)(counts[i] + 1));  // +1 self-loop
}

__global__ void k_scanA(const int* __restrict__ in, int* __restrict__ out, int* __restrict__ bsum) {
    __shared__ int s[256];
    int t = threadIdx.x;
    int i = blockIdx.x * 256 + t;
    int v = in[i];
    s[t] = v;
    __syncthreads();
    for (int off = 1; off < 256; off <<= 1) {
        int x = (t >= off) ? s[t - off] : 0;
        __syncthreads();
        s[t] += x;
        __syncthreads();
    }
    out[i] = s[t] - v;
    if (t == 255) bsum[blockIdx.x] = s[t];
}

__global__ void k_scanB(int* __restrict__ bsum) {
    __shared__ int s[512];
    int t = threadIdx.x;
    int v = bsum[t];
    s[t] = v;
    __syncthreads();
    for (int off = 1; off < 512; off <<= 1) {
        int x = (t >= off) ? s[t - off] : 0;
        __syncthreads();
        s[t] += x;
        __syncthreads();
    }
    bsum[t] = s[t] - v;
}

__global__ void k_scanC(int* __restrict__ rowstart, const int* __restrict__ bsum) {
    int t = threadIdx.x;
    int i = blockIdx.x * 256 + t;
    rowstart[i] += bsum[blockIdx.x];
    if (i == 0) rowstart[NN] = NE;
}

__global__ void k_fill(const int* __restrict__ src, const int* __restrict__ dst,
                       const int* __restrict__ rowstart, int* __restrict__ cursor,
                       const float* __restrict__ dis,
                       int* __restrict__ col, float* __restrict__ wgt) {
    int e = blockIdx.x * blockDim.x + threadIdx.x;
    if (e >= NE) return;
    int s = src[e], d = dst[e];
    int pos = rowstart[d] + atomicAdd(&cursor[d], 1);
    col[pos] = s;
    wgt[pos] = dis[s] * dis[d];
}

// W [CI][CO] fp32 -> WT [CO][KP] bf16 (transposed, zero-padded K)
template<int CI, int CO, int KP>
__global__ void k_prepW(const float* __restrict__ W, ushort* __restrict__ WT) {
    int idx = blockIdx.x * 256 + threadIdx.x;
    if (idx >= CO * KP) return;
    int n = idx / KP, k = idx - n * KP;
    float v = (k < CI) ? W[k * CO + n] : 0.0f;
    WT[idx] = f2bf(v);
}

// x [NN][78] fp32 -> xb [NN][96] bf16 zero-padded
__global__ void k_prepX(const float* __restrict__ x, ushort* __restrict__ xb) {
    int idx = blockIdx.x * 256 + threadIdx.x;   // exact NN*96
    int i = idx / 96, c = idx - i * 96;
    xb[idx] = (c < 78) ? f2bf(x[i * 78 + c]) : (ushort)0;
}

// ---------------- fused layer: gather-agg into LDS, then MFMA GEMM ----------------
// Phase 1: block's 64 node-rows of A = D^-1/2 (A+I) D^-1/2 * h  aggregated straight
//          into XOR-swizzled sA (bf16). 256 threads x (NCH/4) (row,chunk) units.
// Phase 2: panel-loop MFMA, B read directly from L2 (weights are tiny), no barriers.
// hin [NN][KP] bf16, BT [CO][KP] bf16.

template<int KP, int LCH, int CO, int CPO, bool POOL>
__global__ __launch_bounds__(256)
void k_fused(const ushort* __restrict__ hin, const int* __restrict__ rowstart,
             const int* __restrict__ col, const float* __restrict__ wgt,
             const float* __restrict__ dis,
             const ushort* __restrict__ BT, const float* __restrict__ bias,
             const int* __restrict__ batch,
             ushort* __restrict__ hout, float* __restrict__ pooled) {
    constexpr int NCH = KP / 8;           // 16B chunks per row
    constexpr int LP  = LCH * 8;          // LDS row pitch in bf16 elems
    constexpr int NP  = (CO + 63) / 64;   // 64-col panels
    __shared__ ushort sA[64 * LP];

    const int tid  = threadIdx.x;
    const int row0 = blockIdx.x * 64;

    // ---- phase 1: gather-aggregate into sA ----
    for (int id = tid; id < 64 * NCH; id += 256) {
        int r  = id / NCH, kc = id - r * NCH;
        int i  = row0 + r;
        int ch = kc * 8;
        const ushort* gb = hin + ch;

        float d = dis[i];
        bfx8 self = *(const bfx8*)(hin + (size_t)i * KP + ch);
        float acc[8];
        #pragma unroll
        for (int k = 0; k < 8; ++k) acc[k] = d * d * bf2f(self[k]);

        int j = rowstart[i], j1 = rowstart[i + 1];
        for (; j + 4 <= j1; j += 4) {
            int c0 = col[j], c1 = col[j + 1], c2 = col[j + 2], c3 = col[j + 3];
            float w0 = wgt[j], w1 = wgt[j + 1], w2 = wgt[j + 2], w3 = wgt[j + 3];
            bfx8 g0 = *(const bfx8*)(gb + (size_t)c0 * KP);
            bfx8 g1 = *(const bfx8*)(gb + (size_t)c1 * KP);
            bfx8 g2 = *(const bfx8*)(gb + (size_t)c2 * KP);
            bfx8 g3 = *(const bfx8*)(gb + (size_t)c3 * KP);
            #pragma unroll
            for (int k = 0; k < 8; ++k) {
                acc[k] = fmaf(w0, bf2f(g0[k]), acc[k]);
                acc[k] = fmaf(w1, bf2f(g1[k]), acc[k]);
                acc[k] = fmaf(w2, bf2f(g2[k]), acc[k]);
                acc[k] = fmaf(w3, bf2f(g3[k]), acc[k]);
            }
        }
        for (; j < j1; ++j) {
            int c = col[j];
            float w = wgt[j];
            bfx8 g = *(const bfx8*)(gb + (size_t)c * KP);
            #pragma unroll
            for (int k = 0; k < 8; ++k) acc[k] = fmaf(w, bf2f(g[k]), acc[k]);
        }

        bfx8 ov;
        #pragma unroll
        for (int k = 0; k < 8; ++k) ov[k] = (short)f2bf(acc[k]);
        int swz = (kc & ~7) | ((kc & 7) ^ (r & 7));
        *(bfx8*)(sA + r * LP + swz * 8) = ov;
    }
    __syncthreads();

    // ---- phase 2: MFMA panel loop (B direct from L2) ----
    const int lane = tid & 63;
    const int wave = tid >> 6;
    const int wr = wave >> 1, wc = wave & 1;
    const int l15 = lane & 15, l4 = lane >> 4;
    const int r7 = l15 & 7;
    const int rowA0 = wr * 32 + l15;
    const int gbase = row0 + wr * 32;
    const int koff = l4 * 8;

    #pragma unroll
    for (int p = 0; p < NP; ++p) {
        const int bc0 = p * 64 + wc * 32 + l15;
        f32x4 acc[2][2] = {};
        #pragma unroll
        for (int ks = 0; ks < KP / 32; ++ks) {
            int chunk = l4 + ks * 4;
            int swz = (chunk & ~7) | ((chunk & 7) ^ r7);
            int off = swz * 8;
            bfx8 a0 = *(const bfx8*)(sA + rowA0 * LP + off);
            bfx8 a1 = *(const bfx8*)(sA + (rowA0 + 16) * LP + off);
            bfx8 b0 = {0,0,0,0,0,0,0,0}, b1 = {0,0,0,0,0,0,0,0};
            if (bc0 < CO)      b0 = *(const bfx8*)(BT + (size_t)bc0 * KP + koff + ks * 32);
            if (bc0 + 16 < CO) b1 = *(const bfx8*)(BT + (size_t)(bc0 + 16) * KP + koff + ks * 32);
            acc[0][0] = __builtin_amdgcn_mfma_f32_16x16x32_bf16(a0, b0, acc[0][0], 0, 0, 0);
            acc[0][1] = __builtin_amdgcn_mfma_f32_16x16x32_bf16(a0, b1, acc[0][1], 0, 0, 0);
            acc[1][0] = __builtin_amdgcn_mfma_f32_16x16x32_bf16(a1, b0, acc[1][0], 0, 0, 0);
            acc[1][1] = __builtin_amdgcn_mfma_f32_16x16x32_bf16(a1, b1, acc[1][1], 0, 0, 0);
        }

        // epilogue. D-frag: row = fm*16 + (l>>4)*4 + j, col = fn*16 + (l&15).
        if constexpr (POOL) {
            const bool uni = (batch[gbase] == batch[gbase + 31]);
            #pragma unroll
            for (int fn = 0; fn < 2; ++fn) {
                int cg = p * 64 + wc * 32 + fn * 16 + l15;
                bool cok = cg < CO;
                float bs = cok ? bias[cg] : 0.0f;
                if (uni) {
                    float m = -1e30f;
                    #pragma unroll
                    for (int fm = 0; fm < 2; ++fm)
                        #pragma unroll
                        for (int j = 0; j < 4; ++j)
                            m = fmaxf(m, acc[fm][fn][j]);
                    m = fmaxf(m, __shfl_xor(m, 16));
                    m = fmaxf(m, __shfl_xor(m, 32));
                    if (l4 == 0 && cok) {
                        int g = batch[gbase];
                        float v = fmaxf(m + bs, 0.0f);
                        atomicMax((int*)&pooled[g * CO + cg], __float_as_int(v));
                    }
                } else {
                    #pragma unroll
                    for (int fm = 0; fm < 2; ++fm)
                        #pragma unroll
                        for (int j = 0; j < 4; ++j) {
                            if (cok) {
                                int rg = gbase + fm * 16 + l4 * 4 + j;
                                int g = batch[rg];
                                float v = fmaxf(acc[fm][fn][j] + bs, 0.0f);
                                atomicMax((int*)&pooled[g * CO + cg], __float_as_int(v));
                            }
                        }
                }
            }
        } else {
            #pragma unroll
            for (int fn = 0; fn < 2; ++fn) {
                int cg = p * 64 + wc * 32 + fn * 16 + l15;
                if (cg >= CPO) continue;
                float bs = (cg < CO) ? bias[cg] : 0.0f;
                #pragma unroll
                for (int fm = 0; fm < 2; ++fm)
                    #pragma unroll
                    for (int j = 0; j < 4; ++j) {
                        int row = gbase + fm * 16 + l4 * 4 + j;
                        float v = (cg < CO) ? fmaxf(acc[fm][fn][j] + bs, 0.0f) : 0.0f;
                        hout[(size_t)row * CPO + cg] = f2bf(v);
                    }
            }
        }
    }
}

// ---------------- final FC: out[g][c] = fcb[c] + dot(pooled[g,:], fcW[:,c]) ----------

__global__ __launch_bounds__(256)
void k_fc(const float* __restrict__ pooled, const float* __restrict__ fcW,
          const float* __restrict__ fcb, float* __restrict__ out) {
    __shared__ float sp[8][312];
    const int tid = threadIdx.x;
    const int g0 = blockIdx.x * 8;

    for (int k = tid; k < 8 * 312; k += 256)
        ((float*)sp)[k] = pooled[(size_t)g0 * 312 + k];
    __syncthreads();

    const int half = tid >> 7;       // 0..1 -> graphs g0+half*4 .. +3
    const int c = tid & 127;
    float b = fcb[c];
    float acc0 = b, acc1 = b, acc2 = b, acc3 = b;
    const float* wp = fcW + c;
    const float* p0 = sp[half * 4 + 0];
    const float* p1 = sp[half * 4 + 1];
    const float* p2 = sp[half * 4 + 2];
    const float* p3 = sp[half * 4 + 3];
    #pragma unroll 4
    for (int k = 0; k < 312; ++k) {
        float w = wp[(size_t)k * 128];
        acc0 = fmaf(p0[k], w, acc0);
        acc1 = fmaf(p1[k], w, acc1);
        acc2 = fmaf(p2[k], w, acc2);
        acc3 = fmaf(p3[k], w, acc3);
    }
    float* o = out + (size_t)(g0 + half * 4) * 128 + c;
    o[0] = acc0; o[128] = acc1; o[256] = acc2; o[384] = acc3;
}

// ---------------- launch ----------------

extern "C" void kernel_launch(void* const* d_in, const int* in_sizes, int n_in,
                              void* d_out, int out_size, void* d_ws, size_t ws_size,
                              hipStream_t stream) {
    const float* x    = (const float*)d_in[0];
    const int*   ei   = (const int*)d_in[1];
    const int*   srcv = ei;
    const int*   dstv = ei + NE;
    const int*   batch = (const int*)d_in[2];
    const float* W1 = (const float*)d_in[3];
    const float* b1 = (const float*)d_in[4];
    const float* W2 = (const float*)d_in[5];
    const float* b2 = (const float*)d_in[6];
    const float* W3 = (const float*)d_in[7];
    const float* b3 = (const float*)d_in[8];
    const float* fcW = (const float*)d_in[9];
    const float* fcb = (const float*)d_in[10];
    float* out = (float*)d_out;

    char* ws = (char*)d_ws;
    size_t off = 0;
    auto take = [&](size_t bytes) -> void* {
        void* p = ws + off;
        off += (bytes + 255) & ~(size_t)255;
        return p;
    };
    int*    counts   = (int*)take((size_t)NN * 4);
    int*    rowstart = (int*)take((size_t)(NN + 1) * 4);
    int*    cursor   = (int*)take((size_t)NN * 4);
    float*  dis      = (float*)take((size_t)NN * 4);
    int*    bsum     = (int*)take(512 * 4);
    int*    col      = (int*)take((size_t)NE * 4);
    float*  wgt      = (float*)take((size_t)NE * 4);
    ushort* xb       = (ushort*)take((size_t)NN * 96 * 2);
    ushort* h1       = (ushort*)take((size_t)NN * 96 * 2);
    ushort* h2       = (ushort*)take((size_t)NN * 160 * 2);
    float*  pooled   = (float*)take((size_t)NG * 312 * 4);
    ushort* W1T      = (ushort*)take((size_t)78 * 96 * 2);
    ushort* W2T      = (ushort*)take((size_t)156 * 96 * 2);
    ushort* W3T      = (ushort*)take((size_t)312 * 160 * 2);

    hipMemsetAsync(counts, 0, (size_t)NN * 4, stream);
    hipMemsetAsync(cursor, 0, (size_t)NN * 4, stream);
    hipMemsetAsync(pooled, 0, (size_t)NG * 312 * 4, stream);

    k_count<<<NE / 256, 256, 0, stream>>>(dstv, counts);
    k_dis<<<NN / 256, 256, 0, stream>>>(counts, dis);
    k_scanA<<<NN / 256, 256, 0, stream>>>(counts, rowstart, bsum);
    k_scanB<<<1, 512, 0, stream>>>(bsum);
    k_scanC<<<NN / 256, 256, 0, stream>>>(rowstart, bsum);
    k_fill<<<NE / 256, 256, 0, stream>>>(srcv, dstv, rowstart, cursor, dis, col, wgt);

    k_prepW<78, 78, 96><<<(78 * 96 + 255) / 256, 256, 0, stream>>>(W1, W1T);
    k_prepW<78, 156, 96><<<(156 * 96 + 255) / 256, 256, 0, stream>>>(W2, W2T);
    k_prepW<156, 312, 160><<<(312 * 160 + 255) / 256, 256, 0, stream>>>(W3, W3T);
    k_prepX<<<NN * 96 / 256, 256, 0, stream>>>(x, xb);

    // fused layers: gather-agg (phase 1) + MFMA GEMM (phase 2)
    k_fused<96, 16, 78, 96, false><<<NN / 64, 256, 0, stream>>>(
        xb, rowstart, col, wgt, dis, W1T, b1, nullptr, h1, nullptr);
    k_fused<96, 16, 156, 160, false><<<NN / 64, 256, 0, stream>>>(
        h1, rowstart, col, wgt, dis, W2T, b2, nullptr, h2, nullptr);
    k_fused<160, 24, 312, 312, true><<<NN / 64, 256, 0, stream>>>(
        h2, rowstart, col, wgt, dis, W3T, b3, batch, nullptr, pooled);

    // FC (fp32, 8 graphs/block, 512 blocks)
    k_fc<<<NG / 8, 256, 0, stream>>>(pooled, fcW, fcb, out);
}